// Round 17
// baseline (475.687 us; speedup 1.0000x reference)
//
#include <hip/hip_runtime.h>
#include <hip/hip_bf16.h>
#include <math.h>

// Problem constants
#define B_    4
#define S_    2048
#define D_    512
#define H_    8
#define DH_   64
#define E_    8
#define HID_  1365
#define HIDP_ 1408
#define CAP_  1024
#define TOK_  (B_*S_)
#define NASS_ (B_*2*S_)
#define RMAX_ (NASS_ + 8*128)
#define NQKU_ 1152   // q(512) | k(512) | U(128)
#define C11   (1.0f/2048.0f)
#define C22   (1.0f/(2048.0f*2048.0f))

typedef __attribute__((ext_vector_type(8))) short bf16x8;
typedef __attribute__((ext_vector_type(8))) _Float16 f16x8;
typedef __attribute__((ext_vector_type(2))) __fp16 h16x2;   // cvt_pkrtz result type
typedef __attribute__((ext_vector_type(4))) float f32x4;
typedef __hip_bfloat16 bf16;
typedef _Float16 f16;

#define MFMA16(a, b, c) __builtin_amdgcn_mfma_f32_16x16x32_bf16(a, b, c, 0, 0, 0)
#define MFMAH(a, b, c)  __builtin_amdgcn_mfma_f32_16x16x32_f16(a, b, c, 0, 0, 0)

__device__ __forceinline__ void gload16(const void* g, void* l) {
  __builtin_amdgcn_global_load_lds(
      (const __attribute__((address_space(1))) unsigned int*)g,
      (__attribute__((address_space(3))) unsigned int*)l, 16, 0, 0);
}

__device__ __forceinline__ unsigned bf16pk(float a, float b) {
  unsigned ua = __float_as_uint(a); ua = (ua + 0x7FFF + ((ua >> 16) & 1)) >> 16;
  unsigned ub = __float_as_uint(b); ub = (ub + 0x7FFF + ((ub >> 16) & 1)) >> 16;
  return ua | (ub << 16);
}

__device__ __forceinline__ unsigned short h2us(f16 h) {
  return *(unsigned short*)&h;
}

// ---------------------------------------------------------------------------
// fp32 -> bf16 elementwise
// ---------------------------------------------------------------------------
__global__ __launch_bounds__(256) void cvt_bf16(const float* __restrict__ in,
                                                bf16* __restrict__ out, int n) {
  int i = (blockIdx.x * 256 + threadIdx.x) * 4;
  if (i < n) {
    float4 v = *(const float4*)(in + i);
    uint2 pk; pk.x = bf16pk(v.x, v.y); pk.y = bf16pk(v.z, v.w);
    *(uint2*)((unsigned short*)out + i) = pk;
  }
}

// ---------------------------------------------------------------------------
// fp32 -> fp16 elementwise
// ---------------------------------------------------------------------------
__global__ __launch_bounds__(256) void cvt_f16(const float* __restrict__ in,
                                               f16* __restrict__ out, int n) {
  int i = (blockIdx.x * 256 + threadIdx.x) * 4;
  if (i < n) {
    float4 v = *(const float4*)(in + i);
    ushort4 o;
    ((unsigned short*)&o)[0] = h2us((f16)v.x);
    ((unsigned short*)&o)[1] = h2us((f16)v.y);
    ((unsigned short*)&o)[2] = h2us((f16)v.z);
    ((unsigned short*)&o)[3] = h2us((f16)v.w);
    *(ushort4*)((unsigned short*)out + i) = o;
  }
}

// ---------------------------------------------------------------------------
// fp32 -> (hi, lo*2048) fp16 split-2
// ---------------------------------------------------------------------------
__global__ __launch_bounds__(256) void split2h(const float* __restrict__ in,
    unsigned short* __restrict__ ph, unsigned short* __restrict__ pl, int n) {
  int i = (blockIdx.x * 256 + threadIdx.x) * 4;
  if (i >= n) return;
  float4 v = *(const float4*)(in + i);
  float a[4] = {v.x, v.y, v.z, v.w};
  ushort4 hh, ll;
#pragma unroll
  for (int j = 0; j < 4; j++) {
    f16 h = (f16)a[j];
    float r = (a[j] - (float)h) * 2048.f;
    f16 l = (f16)r;
    ((unsigned short*)&hh)[j] = h2us(h);
    ((unsigned short*)&ll)[j] = h2us(l);
  }
  *(ushort4*)(ph + i) = hh;
  *(ushort4*)(pl + i) = ll;
}

// ---------------------------------------------------------------------------
// W1 [e][512][1365] fp32 -> W1t [e][1408][512] bf16 (zero pad)
// ---------------------------------------------------------------------------
__global__ __launch_bounds__(256) void transpose_w1(const float* __restrict__ W1,
                                                    bf16* __restrict__ W1t) {
  __shared__ float t[32][33];
  int e = blockIdx.z;
  int n0 = blockIdx.x * 32, d0 = blockIdx.y * 32;
  int tx = threadIdx.x & 31, ty = threadIdx.x >> 5;
  const float* in = W1 + (size_t)e * D_ * HID_;
  bf16* out = W1t + (size_t)e * HIDP_ * D_;
#pragma unroll
  for (int j = 0; j < 4; j++) {
    int d = d0 + ty + j * 8, n = n0 + tx;
    t[ty + j * 8][tx] = (n < HID_) ? in[(size_t)d * HID_ + n] : 0.f;
  }
  __syncthreads();
#pragma unroll
  for (int j = 0; j < 4; j++) {
    int n = n0 + ty + j * 8, d = d0 + tx;
    out[(size_t)n * D_ + d] = __float2bfloat16(t[tx][ty + j * 8]);
  }
}

// ---------------------------------------------------------------------------
// W2 [e][1365][512] fp32 -> W2t [e][512][1408] bf16 (zero pad)
// ---------------------------------------------------------------------------
__global__ __launch_bounds__(256) void transpose_w2(const float* __restrict__ W2,
                                                    bf16* __restrict__ W2t) {
  __shared__ float t[32][33];
  int e = blockIdx.z;
  int n0 = blockIdx.x * 32, k0 = blockIdx.y * 32;
  int tx = threadIdx.x & 31, ty = threadIdx.x >> 5;
  const float* in = W2 + (size_t)e * HID_ * D_;
  bf16* out = W2t + (size_t)e * D_ * HIDP_;
#pragma unroll
  for (int j = 0; j < 4; j++) {
    int k = k0 + ty + j * 8;
    t[ty + j * 8][tx] = (k < HID_) ? in[(size_t)k * D_ + n0 + tx] : 0.f;
  }
  __syncthreads();
#pragma unroll
  for (int j = 0; j < 4; j++) {
    int n = n0 + ty + j * 8, k = k0 + tx;
    out[(size_t)n * HIDP_ + k] = __float2bfloat16(t[tx][ty + j * 8]);
  }
}

// ---------------------------------------------------------------------------
// 2-byte transpose: vbuf [8192][512] -> vT [b*8+h][64][2048]
// ---------------------------------------------------------------------------
__global__ __launch_bounds__(256) void transpose_v(const unsigned short* __restrict__ vbuf,
                                                   unsigned short* __restrict__ vT) {
  __shared__ unsigned short t[32][33];
  int bh = blockIdx.z;
  int b = bh >> 3, h = bh & 7;
  int s0 = blockIdx.x * 32, d0 = blockIdx.y * 32;
  int tx = threadIdx.x & 31, ty = threadIdx.x >> 5;
  const unsigned short* in = vbuf + (size_t)b * S_ * D_ + h * DH_;
#pragma unroll
  for (int j = 0; j < 4; j++)
    t[ty + j * 8][tx] = in[(size_t)(s0 + ty + j * 8) * D_ + d0 + tx];
  __syncthreads();
  unsigned short* out = vT + (size_t)bh * DH_ * S_;
#pragma unroll
  for (int j = 0; j < 4; j++)
    out[(size_t)(d0 + ty + j * 8) * S_ + s0 + tx] = t[tx][ty + j * 8];
}

// ---------------------------------------------------------------------------
// transpose_u: qku32 cols 1024..1151 -> U2T [(b*8+h)*16 + r][2048] fp16,
// rows r=0..7 = hi(U[e=r]), rows 8..15 = lo*2048. grid (32, 4), 256 thr.
// ---------------------------------------------------------------------------
__global__ __launch_bounds__(256) void transpose_u(const float* __restrict__ qku,
                                                   f16* __restrict__ U2T) {
  __shared__ float t[64][132];
  int b = blockIdx.y;
  int s0 = blockIdx.x * 64;
  int tid = threadIdx.x;
#pragma unroll
  for (int p = 0; p < 8; p++) {
    int i = tid + p * 256;
    int tok = i >> 5, c4 = i & 31;
    float4 v = *(const float4*)(qku + (size_t)(b * 2048 + s0 + tok) * NQKU_ + 1024 + c4 * 4);
    t[tok][c4 * 4 + 0] = v.x; t[tok][c4 * 4 + 1] = v.y;
    t[tok][c4 * 4 + 2] = v.z; t[tok][c4 * 4 + 3] = v.w;
  }
  __syncthreads();
  int row = tid >> 1, sh = tid & 1;
  int h = row >> 4, rr = row & 15;
  int e = rr & 7;
  bool lo = rr >= 8;
  f16* dst = U2T + ((size_t)((b * 8 + h) * 16 + rr) * 2048 + s0 + sh * 32);
  for (int i = 0; i < 32; i++) {
    float v = t[sh * 32 + i][h * 8 + e];
    f16 hh = (f16)v;
    f16 outv = lo ? (f16)((v - (float)hh) * 2048.f) : hh;
    dst[i] = outv;
  }
}

// ---------------------------------------------------------------------------
// MFMA GEMM NT bf16. 128x128 tile, BK=64, 256 thr (4 waves 2x2).
// MODE 1: Wo (bias+resid, out fp32)  MODE 2: FFN1 (LeakyReLU, out bf16)
// MODE 3: FFN2 (bias, out bf16)
// ---------------------------------------------------------------------------
template <int MODE>
__global__ __launch_bounds__(256) void gemm_mfma(
    const bf16* __restrict__ A, const bf16* __restrict__ Bt,
    const float* __restrict__ bias, const float* __restrict__ resid,
    void* __restrict__ Cout, int N, int K,
    const int* __restrict__ ebase, const int* __restrict__ ecnt) {
  __shared__ bf16 Al[128 * 64];
  __shared__ bf16 Bl[128 * 64];
  int tid = threadIdx.x;
  int w = tid >> 6, lane = tid & 63;
  int lg = lane >> 4, li = lane & 15;
  int e = 0;
  size_t arow0;
  if constexpr (MODE >= 2) {
    e = blockIdx.z;
    int r0 = blockIdx.y * 128;
    if (r0 >= ecnt[e]) return;
    arow0 = (size_t)(ebase[e] + r0);
  } else {
    arow0 = (size_t)blockIdx.y * 128;
  }
  int n0 = blockIdx.x * 128;
  const bf16* Bexp = Bt + (size_t)e * N * K;

  int rowA[4], scA[4];
#pragma unroll
  for (int j = 0; j < 4; j++) {
    int o = w * 4096 + j * 1024 + lane * 16;
    rowA[j] = o >> 7;
    scA[j] = ((o >> 4) & 7) ^ (rowA[j] & 7);
  }
  int wm = w >> 1, wn = w & 1;
  f32x4 acc[4][4] = {};

  for (int k0 = 0; k0 < K; k0 += 64) {
#pragma unroll
    for (int j = 0; j < 4; j++) {
      int o = w * 4096 + j * 1024 + lane * 16;
      gload16(A + (arow0 + rowA[j]) * (size_t)K + k0 + scA[j] * 8, (char*)Al + o);
      gload16(Bexp + (size_t)(n0 + rowA[j]) * K + k0 + scA[j] * 8, (char*)Bl + o);
    }
    __syncthreads();
#pragma unroll
    for (int ks = 0; ks < 2; ks++) {
      bf16x8 af[4], bfr[4];
#pragma unroll
      for (int mi = 0; mi < 4; mi++) {
        int row = wm * 64 + mi * 16 + li;
        int cb = (lg * 16 + ks * 64) ^ ((row & 7) << 4);
        af[mi] = *(const bf16x8*)((char*)Al + row * 128 + cb);
      }
#pragma unroll
      for (int ni = 0; ni < 4; ni++) {
        int row = wn * 64 + ni * 16 + li;
        int cb = (lg * 16 + ks * 64) ^ ((row & 7) << 4);
        bfr[ni] = *(const bf16x8*)((char*)Bl + row * 128 + cb);
      }
#pragma unroll
      for (int mi = 0; mi < 4; mi++)
#pragma unroll
        for (int ni = 0; ni < 4; ni++)
          acc[mi][ni] = MFMA16(af[mi], bfr[ni], acc[mi][ni]);
    }
    __syncthreads();
  }

#pragma unroll
  for (int mi = 0; mi < 4; mi++) {
#pragma unroll
    for (int ni = 0; ni < 4; ni++) {
#pragma unroll
      for (int r = 0; r < 4; r++) {
        size_t m = arow0 + wm * 64 + mi * 16 + lg * 4 + r;
        int c = n0 + wn * 64 + ni * 16 + li;
        float v = acc[mi][ni][r];
        if constexpr (MODE == 1) {
          v += bias[c] + resid[m * (size_t)N + c];
          ((float*)Cout)[m * (size_t)N + c] = v;
        } else if constexpr (MODE == 2) {
          if (c < HID_) {
            v += bias[e * HID_ + c];
            v = (v > 0.f) ? v : 0.01f * v;
            ((bf16*)Cout)[m * (size_t)HIDP_ + c] = __float2bfloat16(v);
          } else {
            ((bf16*)Cout)[m * (size_t)HIDP_ + c] = __float2bfloat16(0.f);
          }
        } else {
          v += bias[e * D_ + c];
          ((bf16*)Cout)[m * (size_t)N + c] = __float2bfloat16(v);
        }
      }
    }
  }
}

// ---------------------------------------------------------------------------
// fp16 GEMM NT (v-projection): C fp16 = A*Bt^T + bias. 128x128, BK=64.
// ---------------------------------------------------------------------------
__global__ __launch_bounds__(256) void gemm_vf16(
    const f16* __restrict__ A, const f16* __restrict__ Bt,
    const float* __restrict__ bias, f16* __restrict__ Cout, int N, int K) {
  __shared__ f16 Al[128 * 64];
  __shared__ f16 Bl[128 * 64];
  int tid = threadIdx.x;
  int w = tid >> 6, lane = tid & 63;
  int lg = lane >> 4, li = lane & 15;
  size_t arow0 = (size_t)blockIdx.y * 128;
  int n0 = blockIdx.x * 128;

  int rowA[4], scA[4];
#pragma unroll
  for (int j = 0; j < 4; j++) {
    int o = w * 4096 + j * 1024 + lane * 16;
    rowA[j] = o >> 7;
    scA[j] = ((o >> 4) & 7) ^ (rowA[j] & 7);
  }
  int wm = w >> 1, wn = w & 1;
  f32x4 acc[4][4] = {};

  for (int k0 = 0; k0 < K; k0 += 64) {
#pragma unroll
    for (int j = 0; j < 4; j++) {
      int o = w * 4096 + j * 1024 + lane * 16;
      gload16(A + (arow0 + rowA[j]) * (size_t)K + k0 + scA[j] * 8, (char*)Al + o);
      gload16(Bt + (size_t)(n0 + rowA[j]) * K + k0 + scA[j] * 8, (char*)Bl + o);
    }
    __syncthreads();
#pragma unroll
    for (int ks = 0; ks < 2; ks++) {
      f16x8 af[4], bfr[4];
#pragma unroll
      for (int mi = 0; mi < 4; mi++) {
        int row = wm * 64 + mi * 16 + li;
        int cb = (lg * 16 + ks * 64) ^ ((row & 7) << 4);
        af[mi] = *(const f16x8*)((char*)Al + row * 128 + cb);
      }
#pragma unroll
      for (int ni = 0; ni < 4; ni++) {
        int row = wn * 64 + ni * 16 + li;
        int cb = (lg * 16 + ks * 64) ^ ((row & 7) << 4);
        bfr[ni] = *(const f16x8*)((char*)Bl + row * 128 + cb);
      }
#pragma unroll
      for (int mi = 0; mi < 4; mi++)
#pragma unroll
        for (int ni = 0; ni < 4; ni++)
          acc[mi][ni] = MFMAH(af[mi], bfr[ni], acc[mi][ni]);
    }
    __syncthreads();
  }
#pragma unroll
  for (int mi = 0; mi < 4; mi++)
#pragma unroll
    for (int ni = 0; ni < 4; ni++)
#pragma unroll
      for (int r = 0; r < 4; r++) {
        size_t m = arow0 + wm * 64 + mi * 16 + lg * 4 + r;
        int c = n0 + wn * 64 + ni * 16 + li;
        Cout[m * (size_t)N + c] = (f16)(acc[mi][ni][r] + bias[c]);
      }
}

// ---------------------------------------------------------------------------
// fp16 split-2 high-precision GEMM, BK=64: C fp32 = A*Bt^T via 3 fp16 MFMA
// products, dual accumulators. XCD-swizzled (grid must be 9 x 64).
// ---------------------------------------------------------------------------
__global__ __launch_bounds__(256) void gemm_split2(
    const f16* __restrict__ Ah, const f16* __restrict__ Als,
    const f16* __restrict__ Bh, const f16* __restrict__ Bls,
    const float* __restrict__ bias, float* __restrict__ C, int N, int K) {
  __shared__ f16 As[2][128 * 64];
  __shared__ f16 Bs[2][128 * 64];
  int tid = threadIdx.x;
  int w = tid >> 6, lane = tid & 63;
  int lg = lane >> 4, li = lane & 15;
  // swizzle: all 9 x-tiles of one y-panel on the same XCD (lin%8 fixed)
  int lin = blockIdx.y * gridDim.x + blockIdx.x;
  int aa = lin / 72, t = lin % 72;
  size_t m0 = (size_t)((t & 7) + 8 * aa) * 128;
  int n0 = (t >> 3) * 128;
  int wm = w >> 1, wn = w & 1;
  f32x4 accA[4][4] = {};
  f32x4 accB[4][4] = {};

  int rowA[4], scA[4];
#pragma unroll
  for (int j = 0; j < 4; j++) {
    int o = w * 4096 + j * 1024 + lane * 16;
    rowA[j] = o >> 7;
    scA[j] = ((o >> 4) & 7) ^ (rowA[j] & 7);
  }

  for (int k0 = 0; k0 < K; k0 += 64) {
#pragma unroll
    for (int j = 0; j < 4; j++) {
      int o = w * 4096 + j * 1024 + lane * 16;
      size_t sa = (m0 + rowA[j]) * (size_t)K + k0 + scA[j] * 8;
      size_t sb = ((size_t)n0 + rowA[j]) * K + k0 + scA[j] * 8;
      gload16(Ah + sa, (char*)As[0] + o);
      gload16(Als + sa, (char*)As[1] + o);
      gload16(Bh + sb, (char*)Bs[0] + o);
      gload16(Bls + sb, (char*)Bs[1] + o);
    }
    __syncthreads();
#pragma unroll
    for (int ks = 0; ks < 2; ks++) {
      f16x8 afh[4], afl[4], bfh[4], bfl[4];
#pragma unroll
      for (int mi = 0; mi < 4; mi++) {
        int row = wm * 64 + mi * 16 + li;
        int cb = (lg * 16 + ks * 64) ^ ((row & 7) << 4);
        afh[mi] = *(const f16x8*)((char*)As[0] + row * 128 + cb);
        afl[mi] = *(const f16x8*)((char*)As[1] + row * 128 + cb);
      }
#pragma unroll
      for (int ni = 0; ni < 4; ni++) {
        int row = wn * 64 + ni * 16 + li;
        int cb = (lg * 16 + ks * 64) ^ ((row & 7) << 4);
        bfh[ni] = *(const f16x8*)((char*)Bs[0] + row * 128 + cb);
        bfl[ni] = *(const f16x8*)((char*)Bs[1] + row * 128 + cb);
      }
#pragma unroll
      for (int mi = 0; mi < 4; mi++)
#pragma unroll
        for (int ni = 0; ni < 4; ni++) {
          accA[mi][ni] = MFMAH(afh[mi], bfh[ni], accA[mi][ni]);
          accB[mi][ni] = MFMAH(afh[mi], bfl[ni], accB[mi][ni]);
          accB[mi][ni] = MFMAH(afl[mi], bfh[ni], accB[mi][ni]);
        }
    }
    __syncthreads();
  }
#pragma unroll
  for (int mi = 0; mi < 4; mi++)
#pragma unroll
    for (int ni = 0; ni < 4; ni++)
#pragma unroll
      for (int r = 0; r < 4; r++) {
        size_t m = m0 + wm * 64 + mi * 16 + lg * 4 + r;
        int c = n0 + wn * 64 + ni * 16 + li;
        C[m * (size_t)N + c] = accA[mi][ni][r] + accB[mi][ni][r] * C11 + bias[c];
      }
}

// ---------------------------------------------------------------------------
// ksplit: k-part of qku32 (cols 512..1023) -> head-major fp16 split-2
// [bh][2048][64] (hi, lo*2048)
// ---------------------------------------------------------------------------
__global__ __launch_bounds__(256) void ksplit(const float* __restrict__ qku,
    unsigned short* __restrict__ kh, unsigned short* __restrict__ kls) {
  int gid = blockIdx.x * 256 + threadIdx.x;
  int idx4 = gid * 4;
  int t = idx4 >> 9, c = idx4 & 511;
  int h = c >> 6, d = c & 63;
  int b = t >> 11, s = t & 2047;
  float4 v = *(const float4*)(qku + (size_t)t * NQKU_ + 512 + c);
  float a[4] = {v.x, v.y, v.z, v.w};
  ushort4 hh, ll;
#pragma unroll
  for (int j = 0; j < 4; j++) {
    f16 hv = (f16)a[j];
    f16 lv = (f16)((a[j] - (float)hv) * 2048.f);
    ((unsigned short*)&hh)[j] = h2us(hv);
    ((unsigned short*)&ll)[j] = h2us(lv);
  }
  size_t o = (((size_t)(b * 8 + h) * S_ + s) * 64 + d);
  *(ushort4*)(kh + o) = hh;
  *(ushort4*)(kls + o) = ll;
}

// ---------------------------------------------------------------------------
// Wg2[d][e] = sum_n Wo[n][d] * Wg[n][e]
// ---------------------------------------------------------------------------
__global__ __launch_bounds__(256) void wg2_kernel(const float* __restrict__ Wo,
                                                  const float* __restrict__ Wg,
                                                  float* __restrict__ Wg2) {
  int gid = blockIdx.x * 256 + threadIdx.x;
  int d = gid >> 3, e = gid & 7;
  float acc = 0.f;
  for (int n = 0; n < D_; n++) acc += Wo[(size_t)n * D_ + d] * Wg[n * E_ + e];
  Wg2[d * E_ + e] = acc;
}

// ---------------------------------------------------------------------------
// Wu[(h*8+e)][d] = sum_c Wqkv[1024+h*64+c][d] * Wg2[(h*64+c)][e]; rows 64..127=0
// Also assembles bfull = concat(bqkv[0:1024], bU[128]).
// ---------------------------------------------------------------------------
__global__ __launch_bounds__(256) void wu_kernel(const float* __restrict__ Wqkv,
    const float* __restrict__ Wg2, const float* __restrict__ bqkv,
    float* __restrict__ Wu, float* __restrict__ bfull) {
  int gid = blockIdx.x * 256 + threadIdx.x;
  int row = gid >> 9, d = gid & 511;
  float acc = 0.f;
  if (row < 64) {
    int h = row >> 3, e = row & 7;
    const float* wv = Wqkv + (size_t)(1024 + h * 64) * 512 + d;
    const float* wg = Wg2 + h * 64 * 8 + e;
    for (int c = 0; c < 64; c++) acc += wv[(size_t)c * 512] * wg[c * 8];
  }
  Wu[gid] = acc;
  if (gid < 1024) bfull[gid] = bqkv[gid];
  if (gid < 128) {
    float bacc = 0.f;
    if (gid < 64) {
      int h = gid >> 3, e = gid & 7;
      for (int c = 0; c < 64; c++)
        bacc += bqkv[1024 + h * 64 + c] * Wg2[(h * 64 + c) * 8 + e];
    }
    bfull[1024 + gid] = bacc;
  }
}

// ---------------------------------------------------------------------------
// xwg: logits init = (x[t]+bo) @ Wg
// ---------------------------------------------------------------------------
__global__ __launch_bounds__(256) void xwg_kernel(const float* __restrict__ x,
                                                  const float* __restrict__ bo,
                                                  const float* __restrict__ Wg,
                                                  float* __restrict__ logits) {
  int tid = threadIdx.x;
  int tl = tid >> 3, j = tid & 7;
  int t = blockIdx.x * 32 + tl;
  const float* xr = x + (size_t)t * D_;
  float part[8] = {0, 0, 0, 0, 0, 0, 0, 0};
  for (int d = j; d < D_; d += 8) {
    float xv = xr[d] + bo[d];
    const float* wg = Wg + d * E_;
#pragma unroll
    for (int e = 0; e < 8; e++) part[e] += xv * wg[e];
  }
#pragma unroll
  for (int off = 1; off < 8; off <<= 1)
#pragma unroll
    for (int e = 0; e < 8; e++) part[e] += __shfl_xor(part[e], off);
  if (j == 0) {
#pragma unroll
    for (int e = 0; e < 8; e++) logits[(size_t)t * 8 + e] = part[e];
  }
}

// ---------------------------------------------------------------------------
// attn_fused (fp16 split-2): 4-wave blocks, 64 q-rows, KV tile 64.
// Precise scores (3 products, nb-local dual acc) -> exp2 online softmax
// with defer-max -> (a) PV MFMA -> attnb, (b) P.U MFMA -> part.
// 1D grid 1024 blocks, XCD-swizzled. LDS 31744 B -> up to 5 blocks/CU.
// Staging source pointers hoisted out of the kt loop (pointer increments).
// ---------------------------------------------------------------------------
__global__ __launch_bounds__(256, 4) void attn_fused(
    const float* __restrict__ qku,
    const f16* __restrict__ kh, const f16* __restrict__ kls,
    const f16* __restrict__ vT, const f16* __restrict__ U2T,
    bf16* __restrict__ attnb, float* __restrict__ part) {
  __shared__ f16 Ks0[64 * 64];
  __shared__ f16 Ks1[64 * 64];
  __shared__ f16 Vtl[64 * 64];      // [d][key]
  __shared__ f16 Ut[16 * 64];       // rows 0..7 = U-hi[e], rows 8..15 = U-lo*2048
  __shared__ f16 Pl[4][16 * 40];    // per-wave P, 16 q x 32 keys, stride 80B
  int bid = blockIdx.x;
  int xcd = bid & 7, idx = bid >> 3; // idx 0..127
  int bh = (idx >> 5) * 8 + xcd;     // b = idx>>5, h = xcd
  int qt = idx & 31;
  int b = bh >> 3, h = bh & 7, q0 = qt * 64;
  int tid = threadIdx.x, w = tid >> 6, lane = tid & 63;
  int lg = lane >> 4, qi = lane & 15;
  const float KS = 0.125f * 1.44269504089f;   // exp2 domain
  const float KS2 = KS * C11;

  // q split-2 in-register (hi + lo*2048)
  const float* qsrc = qku + (size_t)(b * S_ + q0 + w * 16 + qi) * NQKU_ + h * 64 + lg * 8;
  f16x8 qh[2], qls[2];
#pragma unroll
  for (int ks = 0; ks < 2; ks++) {
#pragma unroll
    for (int i = 0; i < 8; i++) {
      float xv = qsrc[ks * 32 + i];
      f16 hh = (f16)xv;
      f16 ll = (f16)((xv - (float)hh) * 2048.f);
      qh[ks][i] = hh;
      qls[ks][i] = ll;
    }
  }

  // hoisted staging pointers (advance per kt)
  int o0 = w * 2048 + lane * 16;
  int o1 = o0 + 1024;
  int row0 = o0 >> 7, row1 = o1 >> 7;
  int sc0 = ((o0 >> 4) & 7) ^ (row0 & 7);
  int sc1 = ((o1 >> 4) & 7) ^ (row1 & 7);
  const f16* pK0 = kh + ((size_t)bh * S_ + row0) * 64 + sc0 * 8;
  const f16* pK1 = kh + ((size_t)bh * S_ + row1) * 64 + sc1 * 8;
  const f16* pL0 = kls + ((size_t)bh * S_ + row0) * 64 + sc0 * 8;
  const f16* pL1 = kls + ((size_t)bh * S_ + row1) * 64 + sc1 * 8;
  const f16* Vbase = vT + (size_t)bh * DH_ * S_;
  const f16* pV0 = Vbase + (size_t)row0 * S_ + sc0 * 8;
  const f16* pV1 = Vbase + (size_t)row1 * S_ + sc1 * 8;
  int ou = (w & 1) * 1024 + lane * 16;
  int rowu = ou >> 7;
  int scu = ((ou >> 4) & 7) ^ (rowu & 7);
  const f16* pU = U2T + ((size_t)(bh * 16 + rowu) * 2048 + scu * 8);

  f32x4 oacc[4] = {};
  f32x4 raccA = {0.f, 0.f, 0.f, 0.f};
  f32x4 raccB = {0.f, 0.f, 0.f, 0.f};
  float mrun = -1e30f, lrun = 0.f;
  char* pw = (char*)&Pl[w][0];

  for (int kt = 0; kt < S_ / 64; kt++) {
    // stage K splits + V tile + U tile via pointer increments
    gload16(pK0, (char*)Ks0 + o0);
    gload16(pK1, (char*)Ks0 + o1);
    gload16(pL0, (char*)Ks1 + o0);
    gload16(pL1, (char*)Ks1 + o1);
    gload16(pV0, (char*)Vtl + o0);
    gload16(pV1, (char*)Vtl + o1);
    if (w < 2) gload16(pU, (char*)Ut + ou);
    pK0 += 64 * 64; pK1 += 64 * 64;
    pL0 += 64 * 64; pL1 += 64 * 64;
    pV0 += 64; pV1 += 64; pU += 64;
    __syncthreads();

    // precise scores: 3-product fp16 split-2; lo accumulator is nb-local.
    f32x4 sA[4];
    float tmax = -1e30f;
#pragma unroll
    for (int nb = 0; nb < 4; nb++) {
      f32x4 a = {0.f, 0.f, 0.f, 0.f};
      f32x4 bq = {0.f, 0.f, 0.f, 0.f};
      int row = nb * 16 + qi;
#pragma unroll
      for (int ks = 0; ks < 2; ks++) {
        int cb = (lg * 16 + ks * 64) ^ ((row & 7) << 4);
        f16x8 k0 = *(const f16x8*)((char*)Ks0 + row * 128 + cb);
        f16x8 k1 = *(const f16x8*)((char*)Ks1 + row * 128 + cb);
        a = MFMAH(k0, qh[ks], a);
        bq = MFMAH(k0, qls[ks], bq);
        bq = MFMAH(k1, qh[ks], bq);
      }
#pragma unroll
      for (int r = 0; r < 4; r++) {
        float v = a[r] * KS + bq[r] * KS2;
        sA[nb][r] = v;
        tmax = fmaxf(tmax, v);
      }
    }
    // online softmax with defer-max (THR=8 log2)
    tmax = fmaxf(tmax, __shfl_xor(tmax, 16));
    tmax = fmaxf(tmax, __shfl_xor(tmax, 32));
    float fsc = 1.f;
    if (!__all(tmax <= mrun + 8.f)) {
      float mnew = fmaxf(mrun, tmax);
      fsc = exp2f(mrun - mnew);
      mrun = mnew;
#pragma unroll
      for (int r = 0; r < 4; r++) { raccA[r] *= fsc; raccB[r] *= fsc; }
#pragma unroll
      for (int db = 0; db < 4; db++)
#pragma unroll
        for (int r = 0; r < 4; r++) oacc[db][r] *= fsc;
    }
    float psum = 0.f;
#pragma unroll
    for (int nb = 0; nb < 4; nb++)
#pragma unroll
      for (int r = 0; r < 4; r++) {
        float pv = exp2f(sA[nb][r] - mrun);
        sA[nb][r] = pv;
        psum += pv;
      }
    psum += __shfl_xor(psum, 16);
    psum += __shfl_xor(psum, 32);
    lrun = lrun * fsc + psum;

    // per 32-key chunk (c=0,1): write P hi -> PV + P.U; write P lo -> P.U
#pragma unroll
    for (int c = 0; c < 2; c++) {
      unsigned hw4[4];
#pragma unroll
      for (int nbL = 0; nbL < 2; nbL++)
#pragma unroll
        for (int rp = 0; rp < 2; rp++) {
          int nb = c * 2 + nbL;
          float p0 = sA[nb][rp * 2], p1 = sA[nb][rp * 2 + 1];
          h16x2 hp = __builtin_amdgcn_cvt_pkrtz(p0, p1);
          hw4[nbL * 2 + rp] = *(unsigned*)&hp;
          int keyl = 4 * lg + 2 * rp + 16 * nbL;
          *(unsigned*)(pw + qi * 80 + keyl * 2) = *(unsigned*)&hp;
        }
      f16x8 pf = *(const f16x8*)(pw + qi * 80 + lg * 16);
#pragma unroll
      for (int db = 0; db < 4; db++) {
        int row = db * 16 + qi;
        int cb = (lg * 16 + c * 64) ^ ((row & 7) << 4);
        f16x8 vf = *(const f16x8*)((char*)Vtl + row * 128 + cb);
        oacc[db] = MFMAH(vf, pf, oacc[db]);
      }
      int ua = qi * 128 + ((c * 64 + lg * 16) ^ ((qi & 7) << 4));
      f16x8 uf = *(const f16x8*)((char*)Ut + ua);
      raccA = MFMAH(uf, pf, raccA);
      // P lo into the same slot using cached hi packs
#pragma unroll
      for (int nbL = 0; nbL < 2; nbL++)
#pragma unroll
        for (int rp = 0; rp < 2; rp++) {
          int nb = c * 2 + nbL;
          float p0 = sA[nb][rp * 2], p1 = sA[nb][rp * 2 + 1];
          h16x2 hp = *(h16x2*)&hw4[nbL * 2 + rp];
          float b0 = (float)hp[0], b1 = (float)hp[1];
          h16x2 lp = __builtin_amdgcn_cvt_pkrtz((p0 - b0) * 2048.f, (p1 - b1) * 2048.f);
          int keyl = 4 * lg + 2 * rp + 16 * nbL;
          *(unsigned*)(pw + qi * 80 + keyl * 2) = *(unsigned*)&lp;
        }
      f16x8 pfl = *(const f16x8*)(pw + qi * 80 + lg * 16);
      raccB = MFMAH(uf, pfl, raccB);
    }
    __syncthreads();
  }

  float inv = 1.f / lrun;
  // routing epilogue:
  // raccA(lg<2)=Uh.Ph, raccA(lg>=2)=Uls.Ph, raccB(lg<2)=Uh.Pls, raccB(lg>=2)=Uls.Pls
  f32x4 pA, pB;
#pragma unroll
  for (int r = 0; r < 4; r++) {
    pA[r] = __shfl_xor(raccA[r], 32);
    pB[r] = __shfl_xor(raccB[r], 32);
  }
  if (lg < 2) {
    float* dst = part + ((size_t)bh * S_ + q0 + w * 16 + qi) * 8 + lg * 4;
#pragma unroll
    for (int r = 0; r < 4; r++)
      dst[r] = (raccA[r] + C11 * (pA[r] + raccB[r]) + C22 * pB[r]) * inv;
  }
  // value epilogue: O^T -> O via wave-private 2KB scratch in Ks0
  char* ow = (char*)Ks0 + w * 2048;
#pragma unroll
  for (int db = 0; db < 4; db++)
#pragma unroll
    for (int rp = 0; rp < 2; rp++) {
      int d = db * 16 + lg * 4 + rp * 2;
      unsigned pk = bf16pk(oacc[db][rp * 2] * inv, oacc[db][rp * 2 + 1] * inv);
      int addr = (qi * 128 + d * 2) ^ ((qi & 7) << 4);
      *(unsigned*)(ow + addr) = pk;
    }
#pragma unroll
  for (int j = 0; j < 2; j++) {
    int o = j * 1024 + lane * 16;
    int q = o >> 7;
    int c16 = (o >> 4) & 7;
    int sc = c16 ^ (q & 7);
    bf16x8 vv = *(const bf16x8*)(ow + q * 128 + sc * 16);
    *(bf16x8*)(attnb + ((size_t)(b * S_ + q0 + w * 16 + q)) * D_ + h * DH_ + c16 * 8) = vv;
  }
}

// ---------------------------------------------------------------------------
// reduce_gate: final logits = xwg + sum_h part; decisions + aux stats.
// ---------------------------------------------------------------------------
__global__ __launch_bounds__(256) void reduce_gate(
    const float* __restrict__ xwg, const float* __restrict__ part,
    int* __restrict__ e1a, int* __restrict__ e2a,
    float* __restrict__ g1a, float* __restrict__ g2a, int* __restrict__ use2a,
    float* __restrict__ dacc) {
  int t = blockIdx.x * 256 + threadIdx.x;
  int b = t >> 11, s = t & 2047;
  float lg[8];
#pragma unroll
  for (int e = 0; e < 8; e++) lg[e] = xwg[(size_t)t * 8 + e];
  for (int h = 0; h < 8; h++) {
    const float* pp = part + ((size_t)(b * 8 + h) * S_ + s) * 8;
#pragma unroll
    for (int e = 0; e < 8; e++) lg[e] += pp[e];
  }
  float mx = lg[0];
#pragma unroll
  for (int e = 1; e < 8; e++) mx = fmaxf(mx, lg[e]);
  float p[8], se = 0.f;
#pragma unroll
  for (int e = 0; e < 8; e++) { p[e] = expf(lg[e] - mx); se += p[e]; }
  float inv = 1.f / se;
#pragma unroll
  for (int e = 0; e < 8; e++) p[e] *= inv;
  float lse = logf(se) + mx;
  int a1 = 0; float m1 = p[0];
#pragma unroll
  for (int e = 1; e < 8; e++) if (p[e] > m1) { m1 = p[e]; a1 = e; }
  int a2 = -1; float m2 = -1.f;
#pragma unroll
  for (int e = 0; e < 8; e++) if (e != a1 && p[e] > m2) { m2 = p[e]; a2 = e; }
  e1a[t] = a1; e2a[t] = a2; g1a[t] = m1; g2a[t] = m2;
  use2a[t] = (m2 > 0.2f) ? 1 : 0;
  float z = lse * lse;
  float pr[8];
#pragma unroll
  for (int e = 0; e < 8; e++) pr[e] = p[e];
#pragma unroll
  for (int off = 1; off < 64; off <<= 1) {
#pragma unroll
    for (int e = 0; e < 8; e++) pr[e] += __shfl_xor(pr[e], off);
    z += __shfl_xor(z, off);
  }
  float dcnt[8];
#pragma unroll
  for (int e = 0; e < 8; e++) dcnt[e] = (float)__popcll(__ballot(a1 == e));
  if ((threadIdx.x & 63) == 0) {
#pragma unroll
    for (int e = 0; e < 8; e++) {
      atomicAdd(&dacc[e], dcnt[e]);
      atomicAdd(&dacc[8 + e], pr[e]);
    }
    atomicAdd(&dacc[16], z);
  }
}

// ---------------------------------------------------------------------------
// Capacity scan: exact cumsum order, parallelized (8 waves, 2-pass).
// ---------------------------------------------------------------------------
__global__ __launch_bounds__(512) void scan_kernel(
    const int* __restrict__ e1a, const int* __restrict__ e2a,
    const int* __restrict__ use2a,
    int* __restrict__ posArr, int* __restrict__ kept_be) {
  __shared__ int wcnt[8][8];
  int b = blockIdx.x;
  int w = threadIdx.x >> 6, lane = threadIdx.x & 63;
  unsigned long long below = (1ull << lane) - 1ull;
  int cnt[8] = {0, 0, 0, 0, 0, 0, 0, 0};
  int ev[8], av[8];
#pragma unroll
  for (int it = 0; it < 8; it++) {
    int i = w * 512 + it * 64 + lane;
    int s = i & (S_ - 1);
    int t = b * S_ + s;
    int e, a;
    if (i < S_) { e = e1a[t]; a = 1; }
    else        { e = e2a[t]; a = use2a[t]; }
    ev[it] = e; av[it] = a;
#pragma unroll
    for (int ee = 0; ee < 8; ee++)
      cnt[ee] += __popcll(__ballot(a && (e == ee)));
  }
  if (lane == 0)
#pragma unroll
    for (int ee = 0; ee < 8; ee++) wcnt[w][ee] = cnt[ee];
  __syncthreads();
  int run[8];
#pragma unroll
  for (int ee = 0; ee < 8; ee++) {
    int sB = 0;
    for (int ww = 0; ww < w; ww++) sB += wcnt[ww][ee];
    run[ee] = sB;
  }
#pragma unroll
  for (int it = 0; it < 8; it++) {
    int i = w * 512 + it * 64 + lane;
    int e = ev[it], a = av[it];
    int pos = -1;
#pragma unroll
    for (int ee = 0; ee < 8; ee++) {
      unsigned long long mask = __ballot(a && (e == ee));
      if (a && e == ee) pos = run[ee] + __popcll(mask & below);
      run[ee] += __popcll(mask);
    }
    posArr[b * (2 * S_) + i] = (a && pos < CAP_) ? pos : -1;
  }
  if (w == 7 && lane == 0)
#pragma unroll
    for (int ee = 0; ee < 8; ee++) kept_be[b * 8 + ee] = min(run[ee], CAP_);
}

// ---------------------------------------------------------------------------
// Meta: 128-aligned per-expert bases + aux-loss scalars.
// ---------------------------------------------------------------------------
__global__ void finalize_meta(const int* __restrict__ kept_be,
                              int* __restrict__ ebase, int* __restrict__ bbase,
                              int* __restrict__ ecnt,
                              const float* __restrict__ dacc, float* __restrict__ outs) {
  if (threadIdx.x == 0 && blockIdx.x == 0) {
    int base = 0;
    for (int e = 0; e < 8; e++) {
      int tot = 0;
      for (int b = 0; b < 4; b++) { bbase[b * 8 + e] = tot; tot += kept_be[b * 8 + e]; }
      ecnt[e] = tot;
      ebase[e] = base;
      base += (tot + 127) & ~127;
    }
    float bal = 0.f;
    for (int e = 0; e < 8; e++) bal += (dacc[e] / (float)TOK_) * (dacc[8 + e] / (float)TOK_);
    bal *= (float)E_;
    float z = dacc[16] / (float)TOK_;
    outs[0] = 0.01f * bal + 0.001f * z;
    outs[1] = bal;
    outs[2] = z;
  }
}

// ---------------------------------------------------------------------------
// Scatter: compacted row lists + per-token combine info.
// ---------------------------------------------------------------------------
__global__ __launch_bounds__(256) void scatter_kernel(
    const int* __restrict__ posArr, const int* __restrict__ e1a, const int* __restrict__ e2a,
    const float* __restrict__ g1a, const float* __restrict__ g2a,
    const int* __restrict__ ebase, const int* __restrict__ bbase,
    int* __restrict__ rowtok, int* __restrict__ rowexp,
    int* __restrict__ tokidx, float* __restrict__ tokw) {
  int gi = blockIdx.x * 256 + threadIdx.x;
  int b = gi >> 12, i = gi & 4095;
  int k = i >> 11, s = i & (S_ - 1);
  int t = b * S_ + s;
  int pos = posArr[gi];
  int idx = -1; float w = 0.f;
  if (pos >= 0) {
    int e = k ? e2a[t] : e1a[t];
    idx = ebase[e] + bbase[b * 8 + e] + pos;
    rowtok[idx] = t;
    rowexp[idx] = e;
    w = k ? g2a[t] : g1a[t];
  }
  tokidx[k * TOK_ + t] = idx;
  tokw[k * TOK_ + t] = w;
}

// ---------------------------------------------------------------------------
// LayerNorm per compacted row -> bf16.
// ---------------------------------------------------------------------------
__global__ __launch_bounds__(256) void ln_kernel(
    const float* __restrict__ o2, const int* __restrict__ rowtok,
    const int* __restrict__ rowexp, const float* __restrict__ ln_g,
    const float* __restrict__ ln_b, bf16* __restrict__ xn) {
  int row = blockIdx.x * 4 + (threadIdx.x >> 6);
  int lane = threadIdx.x & 63;
  int tok = rowtok[row];
  if (tok < 0) return;
  int e = rowexp[row];
  const float* xr = o2 + (size_t)tok * D_;
  float v[8], sum = 0.f, sq = 0.f;
#pragma unroll
  for (int j = 0; j < 8; j++) { v[j] = xr[lane * 8 + j]; sum += v[j]; sq += v[j] * v[j]; }
#pragma unroll
  for (int off = 1; off < 64; off <<= 1) { sum += __shfl_xor(sum, off); sq += __shfl_xor(sq, off); }
  float mu = sum / (float)D_;
  float var = sq / (float)D_ - mu * mu;
  float inv = rsqrtf(var + 1e-5f);
  bf16* xo = xn + (size_t)row * D_;
#pragma unroll
  for (int j = 0; j < 8; j++) {
    int d = lane * 8 + j;
    xo[d] = __float2bfloat16((v[j] - mu) * inv * ln_g[e * D_ + d] + ln_b[e * D_ + d]);
  }
}

// ---------------------------------------------------------------------------
// Combine: out = o2 + w1*y[idx1] + w2*y[idx2]   (y bf16)
// ---------------------------------------------------------------------------
__global__ __launch_bounds__(256) void combine_kernel(
    const float* __restrict__ o2, const bf16* __restrict__ y,
    const int* __restrict__ tokidx, const float* __restrict__ tokw,
    float* __restrict__ out) {
  size_t gi = (size_t)blockIdx.x * 256 + threadIdx.x;
  int t = (int)(gi >> 9);
  int d = (int)(gi & (D_ - 1));
  float v = o2[gi];
  int i1 = tokidx[t], i2 = tokidx[TOK_ + t];
  if (i1 >= 0) v += tokw[t] * __bfloat162float(y[(size_t)i1 * D_ + d]);
  if (i2 >= 0) v += tokw[TOK_ + t] * __bfloat162float(y[(size_t)i2 * D_ + d]);
  out[gi] = v;
}

// ---------------------------------------------------------------------------
extern "C" void kernel_launch(void* const* d_in, const int* in_sizes, int n_in,
                              void* d_out, int out_size, void* d_ws, size_t ws_size,
                              hipStream_t stream) {
  const float* x    = (const float*)d_in[0];
  const float* Wqkv = (const float*)d_in[1];
  const float* bqkv = (const float*)d_in[2];
  const float* Wo   = (const float*)d_in[3];
  const float* bo   = (const float*)d_in[4];
  const float* Wg   = (const float*)d_in[5];
  const float* ln_g = (const float*)d_in[6];
  const float* ln_b = (const float*)d_in[7];
  const float* W1   = (const float*)d_in[8];
  const float* b1   = (const float*)d_in[9];
  const float* W2   = (const float*)d_in[10];
  const float* b2   = (const float*)d_in[11];
  float* out = (float*)d_out;

  char* ws = (char*)d_ws;
  size_t off = 0;
  auto alloc = [&](size_t bytes) -> void* {
    void* p = ws + off;
    off = (off + bytes + 255) & ~(size_t)255;
    return p;
  };
  float* qku32 = (float*)alloc((size_t)TOK_ * NQKU_ * 4); // 37.7 MB
  f16*  vbuf   = (f16*)alloc((size_t)TOK_ * D_ * 2);
  f16*  vT     = (f16*)alloc((size_t)B_ * H_ * DH_ * S_ * 2);
  bf16* attnb  = (bf16*)alloc((size_t)TOK_ * D_ * 2);
  float* o2    = (float*)alloc((size_t)TOK_ * D_ * 4);
  f16*  xh     = (f16*)alloc((size_t)TOK_ * D_ * 2);
  f16*  xls    = (f16*)alloc((size_t)TOK_ * D_ * 2);
  f16*  Wqh    = (f16*)alloc((size_t)NQKU_ * D_ * 2);
  f16*  Wqls   = (f16*)alloc((size_t)NQKU_ * D_ * 2);
  f16*  Wvh    = (f16*)alloc((size_t)D_ * D_ * 2);
  bf16* Wob    = (bf16*)alloc((size_t)D_ * D_ * 2);
  bf16* W1t    = (bf16*)alloc((size_t)E_ * HIDP_ * D_ * 2);
  bf16* W2t    = (bf16*)alloc((size_t)E_ * D_ * HIDP_ * 2);
  bf16* xn     = (bf16*)alloc((size_t)RMAX_ * D_ * 2);
  bf16* hbuf   = (bf16*)alloc((size_t)RMAX_ * HIDP_ * 2);
  bf16* ybuf   = (bf16*)alloc((size_t)RMAX_ * D_ * 2);
  float* Wg2   = (float*)alloc(D_ * E_ * 4);
  float* Wu    = (float*)alloc((size_t)128 * D_ * 4);
  float* bfull = (float*)alloc(NQKU_ * 4);
  f16*  U2T    = (f16*)alloc((size_t)32 * 16 * 2048 * 2);
  float* logits= (float*)alloc((size_t)TOK_ * 8 * 4);
  float* part  = (float*)alloc((size_t)B_ * H_ * S_ * 8 * 4);
  int*   e1a   = (int*)alloc(TOK_ * 4);
  int*   e2a   = (int*)alloc(TOK_ * 4);
  int*   use2a = (int*)alloc(TOK_ * 4);
  float* g1a   = (float*)alloc(TOK_ * 4);
  float* g2a   = (float*)alloc(TOK_ * 4);
  int*   posArr  = (int*)alloc(NASS_ * 4);
  int*   kept_be = (int*)alloc(32 * 4);
  int*   ebase   = (int*)alloc(8 * 4);
  int*   bbase   = (int*)alloc(32 * 4);
  int*   ecnt    = (int*)alloc(8 * 4);
  int*   rowtok  = (int*)alloc(RMAX_ * 4);
  int*   rowexp  = (int*)alloc(RMAX_ * 4);
  int*   tokidx  = (int*)alloc(NASS_ * 4);
  float* tokw    = (float*)alloc(NASS_ * 4);
  float* dacc    = (float*)alloc(32 * 4);
  // kh/kls alias xh/xls (same size; ksplit runs after all consumers of xh/xls)
  f16* kh  = xh;
  f16* kls = xls;

  hipMemsetAsync(dacc, 0, 32 * 4, stream);
  hipMemsetAsync(rowtok, 0xFF, RMAX_ * 4, stream);

  // ---- prep: splits, weight conversions ----
  split2h<<<TOK_ * D_ / 4 / 256, 256, 0, stream>>>(x, (unsigned short*)xh,
                                                   (unsigned short*)xls, TOK_ * D_);
  split2h<<<1024 * D_ / 4 / 256, 256, 0, stream>>>(Wqkv, (unsigned short*)Wqh,
                                                   (unsigned short*)Wqls, 1024 * D_);
  cvt_f16<<<D_ * D_ / 4 / 256, 256, 0, stream>>>(Wqkv + (size_t)1024 * D_, Wvh, D_ * D_);
  cvt_bf16<<<D_ * D_ / 4 / 256, 256, 0, stream>>>(Wo, Wob, D_ * D_);
  transpose_w1<<<dim3(44, 16, 8), 256, 0, stream>>>(W1, W1t);
  transpose_w2<<<dim3(16, 44, 8), 256, 0, stream>>>(W2, W2t);
  wg2_kernel<<<16, 256, 0, stream>>>(Wo, Wg, Wg2);
  wu_kernel<<<256, 256, 0, stream>>>(Wqkv, Wg2, bqkv, Wu, bfull);
  split2h<<<128 * D_ / 4 / 256, 256, 0, stream>>>(Wu,
      (unsigned short*)(Wqh + (size_t)1024 * D_),
      (unsigned short*)(Wqls + (size_t)1024 * D_), 128 * D_);

  // ---- accurate q,k,U in ONE fp16 split-2 GEMM (N=1152, XCD-swizzled) ----
  gemm_split2<<<dim3(9, 64), 256, 0, stream>>>(xh, xls, Wqh, Wqls,
                                               bfull, qku32, NQKU_, D_);
  // v (value path, fp16 1-product)
  gemm_vf16<<<dim3(4, 64), 256, 0, stream>>>(xh, Wvh, bqkv + 1024, vbuf, D_, D_);
  // routing preps (kh/kls overwrite xh/xls — all consumers above are done)
  ksplit<<<TOK_ * 512 / 4 / 256, 256, 0, stream>>>(qku32, (unsigned short*)kh,
                                                   (unsigned short*)kls);
  transpose_u<<<dim3(32, 4), 256, 0, stream>>>(qku32, U2T);
  xwg_kernel<<<TOK_ / 32, 256, 0, stream>>>(x, bo, Wg, logits);
  transpose_v<<<dim3(64, 2, 32), 256, 0, stream>>>((const unsigned short*)vbuf,
                                                   (unsigned short*)vT);

  // ---- fused attention: value O + routing part in one pass ----
  attn_fused<<<dim3(1024), 256, 0, stream>>>(qku32, kh, kls, vT, U2T,
                                             attnb, part);
  gemm_mfma<1><<<dim3(4, 64), 256, 0, stream>>>(attnb, Wob, bo, x, o2,
                                                D_, D_, nullptr, nullptr);
  // ---- routing reduce + dispatch + expert FFN + combine ----
  reduce_gate<<<TOK_ / 256, 256, 0, stream>>>(logits, part, e1a, e2a, g1a, g2a,
                                              use2a, dacc);
  scan_kernel<<<B_, 512, 0, stream>>>(e1a, e2a, use2a, posArr, kept_be);
  finalize_meta<<<1, 64, 0, stream>>>(kept_be, ebase, bbase, ecnt, dacc,
                                      out + (size_t)TOK_ * D_);
  scatter_kernel<<<NASS_ / 256, 256, 0, stream>>>(posArr, e1a, e2a, g1a, g2a,
                                                  ebase, bbase, rowtok, rowexp,
                                                  tokidx, tokw);
  ln_kernel<<<RMAX_ / 4, 256, 0, stream>>>(o2, rowtok, rowexp, ln_g, ln_b, xn);
  gemm_mfma<2><<<dim3(HIDP_ / 128, 32, E_), 256, 0, stream>>>(xn, W1t, b1, nullptr, hbuf,
                                                              HIDP_, D_, ebase, ecnt);
  gemm_mfma<3><<<dim3(D_ / 128, 32, E_), 256, 0, stream>>>(hbuf, W2t, b2, nullptr, ybuf,
                                                           D_, HIDP_, ebase, ecnt);
  combine_kernel<<<(TOK_ * D_) / 256, 256, 0, stream>>>(o2, ybuf, tokidx, tokw, out);
}

// Round 18
// 433.065 us; speedup vs baseline: 1.0984x; 1.0984x over previous
//
#include <hip/hip_runtime.h>
#include <hip/hip_bf16.h>
#include <math.h>

// Problem constants
#define B_    4
#define S_    2048
#define D_    512
#define H_    8
#define DH_   64
#define E_    8
#define HID_  1365
#define HIDP_ 1408
#define CAP_  1024
#define TOK_  (B_*S_)
#define NASS_ (B_*2*S_)
#define RMAX_ (NASS_ + 8*128)
#define NQKU_ 1152   // q(512) | k(512) | U(128)
#define C11   (1.0f/2048.0f)
#define C22   (1.0f/(2048.0f*2048.0f))

typedef __attribute__((ext_vector_type(8))) short bf16x8;
typedef __attribute__((ext_vector_type(8))) _Float16 f16x8;
typedef __attribute__((ext_vector_type(2))) __fp16 h16x2;   // cvt_pkrtz result type
typedef __attribute__((ext_vector_type(4))) float f32x4;
typedef __hip_bfloat16 bf16;
typedef _Float16 f16;

#define MFMA16(a, b, c) __builtin_amdgcn_mfma_f32_16x16x32_bf16(a, b, c, 0, 0, 0)
#define MFMAH(a, b, c)  __builtin_amdgcn_mfma_f32_16x16x32_f16(a, b, c, 0, 0, 0)

__device__ __forceinline__ void gload16(const void* g, void* l) {
  __builtin_amdgcn_global_load_lds(
      (const __attribute__((address_space(1))) unsigned int*)g,
      (__attribute__((address_space(3))) unsigned int*)l, 16, 0, 0);
}

__device__ __forceinline__ unsigned bf16pk(float a, float b) {
  unsigned ua = __float_as_uint(a); ua = (ua + 0x7FFF + ((ua >> 16) & 1)) >> 16;
  unsigned ub = __float_as_uint(b); ub = (ub + 0x7FFF + ((ub >> 16) & 1)) >> 16;
  return ua | (ub << 16);
}

__device__ __forceinline__ unsigned short h2us(f16 h) {
  return *(unsigned short*)&h;
}

// ===========================================================================
// Device bodies (virtual-block versions) for the fused prep kernels
// ===========================================================================

__device__ __forceinline__ void dev_split2h(const float* __restrict__ in,
    unsigned short* __restrict__ ph, unsigned short* __restrict__ pl,
    int n, int vb) {
  int i = (vb * 256 + threadIdx.x) * 4;
  if (i >= n) return;
  float4 v = *(const float4*)(in + i);
  float a[4] = {v.x, v.y, v.z, v.w};
  ushort4 hh, ll;
#pragma unroll
  for (int j = 0; j < 4; j++) {
    f16 h = (f16)a[j];
    float r = (a[j] - (float)h) * 2048.f;
    f16 l = (f16)r;
    ((unsigned short*)&hh)[j] = h2us(h);
    ((unsigned short*)&ll)[j] = h2us(l);
  }
  *(ushort4*)(ph + i) = hh;
  *(ushort4*)(pl + i) = ll;
}

__device__ __forceinline__ void dev_cvt_f16(const float* __restrict__ in,
                                            f16* __restrict__ out, int n, int vb) {
  int i = (vb * 256 + threadIdx.x) * 4;
  if (i >= n) return;
  float4 v = *(const float4*)(in + i);
  ushort4 o;
  ((unsigned short*)&o)[0] = h2us((f16)v.x);
  ((unsigned short*)&o)[1] = h2us((f16)v.y);
  ((unsigned short*)&o)[2] = h2us((f16)v.z);
  ((unsigned short*)&o)[3] = h2us((f16)v.w);
  *(ushort4*)((unsigned short*)out + i) = o;
}

__device__ __forceinline__ void dev_cvt_bf16(const float* __restrict__ in,
                                             bf16* __restrict__ out, int n, int vb) {
  int i = (vb * 256 + threadIdx.x) * 4;
  if (i >= n) return;
  float4 v = *(const float4*)(in + i);
  uint2 pk; pk.x = bf16pk(v.x, v.y); pk.y = bf16pk(v.z, v.w);
  *(uint2*)((unsigned short*)out + i) = pk;
}

// W1 [e][512][1365] -> W1t [e][1408][512] bf16 (zero pad). vb in [0, 5632)
__device__ __forceinline__ void dev_transpose_w1(const float* __restrict__ W1,
    bf16* __restrict__ W1t, int vb, float* sm) {
  int xg = vb % 44, yg = (vb / 44) % 16, e = vb / 704;
  int n0 = xg * 32, d0 = yg * 32;
  int tx = threadIdx.x & 31, ty = threadIdx.x >> 5;
  const float* in = W1 + (size_t)e * D_ * HID_;
  bf16* out = W1t + (size_t)e * HIDP_ * D_;
#pragma unroll
  for (int j = 0; j < 4; j++) {
    int d = d0 + ty + j * 8, n = n0 + tx;
    sm[(ty + j * 8) * 33 + tx] = (n < HID_) ? in[(size_t)d * HID_ + n] : 0.f;
  }
  __syncthreads();
#pragma unroll
  for (int j = 0; j < 4; j++) {
    int n = n0 + ty + j * 8, d = d0 + tx;
    out[(size_t)n * D_ + d] = __float2bfloat16(sm[tx * 33 + ty + j * 8]);
  }
}

// W2 [e][1365][512] -> W2t [e][512][1408] bf16 (zero pad). vb in [0, 5632)
__device__ __forceinline__ void dev_transpose_w2(const float* __restrict__ W2,
    bf16* __restrict__ W2t, int vb, float* sm) {
  int xg = vb % 16, yg = (vb / 16) % 44, e = vb / 704;
  int n0 = xg * 32, k0 = yg * 32;
  int tx = threadIdx.x & 31, ty = threadIdx.x >> 5;
  const float* in = W2 + (size_t)e * HID_ * D_;
  bf16* out = W2t + (size_t)e * D_ * HIDP_;
#pragma unroll
  for (int j = 0; j < 4; j++) {
    int k = k0 + ty + j * 8;
    sm[(ty + j * 8) * 33 + tx] = (k < HID_) ? in[(size_t)k * D_ + n0 + tx] : 0.f;
  }
  __syncthreads();
#pragma unroll
  for (int j = 0; j < 4; j++) {
    int n = n0 + ty + j * 8, k = k0 + tx;
    out[(size_t)n * HIDP_ + k] = __float2bfloat16(sm[tx * 33 + ty + j * 8]);
  }
}

// Wg2[d][e] = sum_n Wo[n][d] * Wg[n][e]. vb in [0,16)
__device__ __forceinline__ void dev_wg2(const float* __restrict__ Wo,
    const float* __restrict__ Wg, float* __restrict__ Wg2, int vb) {
  int gid = vb * 256 + threadIdx.x;
  int d = gid >> 3, e = gid & 7;
  float acc = 0.f;
  for (int n = 0; n < D_; n++) acc += Wo[(size_t)n * D_ + d] * Wg[n * E_ + e];
  Wg2[d * E_ + e] = acc;
}

// ksplit. vb in [0, 4096)
__device__ __forceinline__ void dev_ksplit(const float* __restrict__ qku,
    unsigned short* __restrict__ kh, unsigned short* __restrict__ kls, int vb) {
  int gid = vb * 256 + threadIdx.x;
  int idx4 = gid * 4;
  int t = idx4 >> 9, c = idx4 & 511;
  int h = c >> 6, d = c & 63;
  int b = t >> 11, s = t & 2047;
  float4 v = *(const float4*)(qku + (size_t)t * NQKU_ + 512 + c);
  float a[4] = {v.x, v.y, v.z, v.w};
  ushort4 hh, ll;
#pragma unroll
  for (int j = 0; j < 4; j++) {
    f16 hv = (f16)a[j];
    f16 lv = (f16)((a[j] - (float)hv) * 2048.f);
    ((unsigned short*)&hh)[j] = h2us(hv);
    ((unsigned short*)&ll)[j] = h2us(lv);
  }
  size_t o = (((size_t)(b * 8 + h) * S_ + s) * 64 + d);
  *(ushort4*)(kh + o) = hh;
  *(ushort4*)(kls + o) = ll;
}

// transpose_u. bx in [0,32), by in [0,4)
__device__ __forceinline__ void dev_transpose_u(const float* __restrict__ qku,
    f16* __restrict__ U2T, int bx, int by, float* sm) {
  int b = by;
  int s0 = bx * 64;
  int tid = threadIdx.x;
#pragma unroll
  for (int p = 0; p < 8; p++) {
    int i = tid + p * 256;
    int tok = i >> 5, c4 = i & 31;
    float4 v = *(const float4*)(qku + (size_t)(b * 2048 + s0 + tok) * NQKU_ + 1024 + c4 * 4);
    sm[tok * 132 + c4 * 4 + 0] = v.x; sm[tok * 132 + c4 * 4 + 1] = v.y;
    sm[tok * 132 + c4 * 4 + 2] = v.z; sm[tok * 132 + c4 * 4 + 3] = v.w;
  }
  __syncthreads();
  int row = tid >> 1, sh = tid & 1;
  int h = row >> 4, rr = row & 15;
  int e = rr & 7;
  bool lo = rr >= 8;
  f16* dst = U2T + ((size_t)((b * 8 + h) * 16 + rr) * 2048 + s0 + sh * 32);
  for (int i = 0; i < 32; i++) {
    float v = sm[(sh * 32 + i) * 132 + h * 8 + e];
    f16 hh = (f16)v;
    f16 outv = lo ? (f16)((v - (float)hh) * 2048.f) : hh;
    dst[i] = outv;
  }
}

// xwg. vb in [0, 256)
__device__ __forceinline__ void dev_xwg(const float* __restrict__ x,
    const float* __restrict__ bo, const float* __restrict__ Wg,
    float* __restrict__ logits, int vb) {
  int tid = threadIdx.x;
  int tl = tid >> 3, j = tid & 7;
  int t = vb * 32 + tl;
  const float* xr = x + (size_t)t * D_;
  float part[8] = {0, 0, 0, 0, 0, 0, 0, 0};
  for (int d = j; d < D_; d += 8) {
    float xv = xr[d] + bo[d];
    const float* wg = Wg + d * E_;
#pragma unroll
    for (int e = 0; e < 8; e++) part[e] += xv * wg[e];
  }
#pragma unroll
  for (int off = 1; off < 8; off <<= 1)
#pragma unroll
    for (int e = 0; e < 8; e++) part[e] += __shfl_xor(part[e], off);
  if (j == 0) {
#pragma unroll
    for (int e = 0; e < 8; e++) logits[(size_t)t * 8 + e] = part[e];
  }
}

// transpose_v. vb in [0, 4096)
__device__ __forceinline__ void dev_transpose_v(
    const unsigned short* __restrict__ vbuf, unsigned short* __restrict__ vT,
    int vb, unsigned short* sm) {
  int xg = vb & 63, yg = (vb >> 6) & 1, bh = vb >> 7;
  int b = bh >> 3, h = bh & 7;
  int s0 = xg * 32, d0 = yg * 32;
  int tx = threadIdx.x & 31, ty = threadIdx.x >> 5;
  const unsigned short* in = vbuf + (size_t)b * S_ * D_ + h * DH_;
#pragma unroll
  for (int j = 0; j < 4; j++)
    sm[(ty + j * 8) * 33 + tx] = in[(size_t)(s0 + ty + j * 8) * D_ + d0 + tx];
  __syncthreads();
  unsigned short* out = vT + (size_t)bh * DH_ * S_;
#pragma unroll
  for (int j = 0; j < 4; j++)
    out[(size_t)(d0 + ty + j * 8) * S_ + s0 + tx] = sm[tx * 33 + ty + j * 8];
}

// ===========================================================================
// prep_a: memsets + split2h(x) + split2h(Wqkv) + cvt_f16 + cvt_bf16 +
//         transpose_w1 + transpose_w2 + wg2.   grid 16469 x 256.
// ===========================================================================
__global__ __launch_bounds__(256) void prep_a(
    const float* __restrict__ x, const float* __restrict__ Wqkv,
    const float* __restrict__ Wo, const float* __restrict__ W1,
    const float* __restrict__ W2, const float* __restrict__ Wg,
    unsigned short* __restrict__ xh, unsigned short* __restrict__ xls,
    unsigned short* __restrict__ Wqh, unsigned short* __restrict__ Wqls,
    f16* __restrict__ Wvh, bf16* __restrict__ Wob,
    bf16* __restrict__ W1t, bf16* __restrict__ W2t, float* __restrict__ Wg2,
    int* __restrict__ rowtok, float* __restrict__ dacc) {
  __shared__ float smem[32 * 33];
  int bid = blockIdx.x;
  if (bid < 68) { rowtok[bid * 256 + threadIdx.x] = -1; return; }
  bid -= 68;
  if (bid < 1) { if (threadIdx.x < 32) dacc[threadIdx.x] = 0.f; return; }
  bid -= 1;
  if (bid < 4096) { dev_split2h(x, xh, xls, TOK_ * D_, bid); return; }
  bid -= 4096;
  if (bid < 512) { dev_split2h(Wqkv, Wqh, Wqls, 1024 * D_, bid); return; }
  bid -= 512;
  if (bid < 256) { dev_cvt_f16(Wqkv + (size_t)1024 * D_, Wvh, D_ * D_, bid); return; }
  bid -= 256;
  if (bid < 256) { dev_cvt_bf16(Wo, Wob, D_ * D_, bid); return; }
  bid -= 256;
  if (bid < 5632) { dev_transpose_w1(W1, W1t, bid, smem); return; }
  bid -= 5632;
  if (bid < 5632) { dev_transpose_w2(W2, W2t, bid, smem); return; }
  bid -= 5632;
  dev_wg2(Wo, Wg, Wg2, bid);
}

// ===========================================================================
// wu2: Wu rows + fused split-2 write into Wqh/Wqls tail + bfull assembly.
// grid 256 x 256.
// ===========================================================================
__global__ __launch_bounds__(256) void wu_kernel2(const float* __restrict__ Wqkv,
    const float* __restrict__ Wg2, const float* __restrict__ bqkv,
    unsigned short* __restrict__ WqhT, unsigned short* __restrict__ WqlsT,
    float* __restrict__ bfull) {
  int gid = blockIdx.x * 256 + threadIdx.x;
  int row = gid >> 9, d = gid & 511;
  float acc = 0.f;
  if (row < 64) {
    int h = row >> 3, e = row & 7;
    const float* wv = Wqkv + (size_t)(1024 + h * 64) * 512 + d;
    const float* wg = Wg2 + h * 64 * 8 + e;
    for (int c = 0; c < 64; c++) acc += wv[(size_t)c * 512] * wg[c * 8];
  }
  f16 hv = (f16)acc;
  f16 lv = (f16)((acc - (float)hv) * 2048.f);
  WqhT[gid] = h2us(hv);
  WqlsT[gid] = h2us(lv);
  if (gid < 1024) bfull[gid] = bqkv[gid];
  if (gid < 128) {
    float bacc = 0.f;
    if (gid < 64) {
      int h = gid >> 3, e = gid & 7;
      for (int c = 0; c < 64; c++)
        bacc += bqkv[1024 + h * 64 + c] * Wg2[(h * 64 + c) * 8 + e];
    }
    bfull[1024 + gid] = bacc;
  }
}

// ===========================================================================
// dev_gemm_split2 (fp16 split-2 q,k,U GEMM) and dev_gemm_vf16 (v GEMM)
// fused into gemm_qv.  grid 832 x 256.  LDS 64 KB shared between branches.
// ===========================================================================
__device__ void dev_gemm_split2(
    const f16* __restrict__ Ah, const f16* __restrict__ Als,
    const f16* __restrict__ Bh, const f16* __restrict__ Bls,
    const float* __restrict__ bias, float* __restrict__ C, int N, int K,
    int lin, f16* sh) {
  f16* As0 = sh;
  f16* As1 = sh + 8192;
  f16* Bs0 = sh + 16384;
  f16* Bs1 = sh + 24576;
  int tid = threadIdx.x;
  int w = tid >> 6, lane = tid & 63;
  int lg = lane >> 4, li = lane & 15;
  int aa = lin / 72, t = lin % 72;
  size_t m0 = (size_t)((t & 7) + 8 * aa) * 128;
  int n0 = (t >> 3) * 128;
  int wm = w >> 1, wn = w & 1;
  f32x4 accA[4][4] = {};
  f32x4 accB[4][4] = {};

  int rowA[4], scA[4];
#pragma unroll
  for (int j = 0; j < 4; j++) {
    int o = w * 4096 + j * 1024 + lane * 16;
    rowA[j] = o >> 7;
    scA[j] = ((o >> 4) & 7) ^ (rowA[j] & 7);
  }

  for (int k0 = 0; k0 < K; k0 += 64) {
#pragma unroll
    for (int j = 0; j < 4; j++) {
      int o = w * 4096 + j * 1024 + lane * 16;
      size_t sa = (m0 + rowA[j]) * (size_t)K + k0 + scA[j] * 8;
      size_t sb = ((size_t)n0 + rowA[j]) * K + k0 + scA[j] * 8;
      gload16(Ah + sa, (char*)As0 + o);
      gload16(Als + sa, (char*)As1 + o);
      gload16(Bh + sb, (char*)Bs0 + o);
      gload16(Bls + sb, (char*)Bs1 + o);
    }
    __syncthreads();
#pragma unroll
    for (int ks = 0; ks < 2; ks++) {
      f16x8 afh[4], afl[4], bfh[4], bfl[4];
#pragma unroll
      for (int mi = 0; mi < 4; mi++) {
        int row = wm * 64 + mi * 16 + li;
        int cb = (lg * 16 + ks * 64) ^ ((row & 7) << 4);
        afh[mi] = *(const f16x8*)((char*)As0 + row * 128 + cb);
        afl[mi] = *(const f16x8*)((char*)As1 + row * 128 + cb);
      }
#pragma unroll
      for (int ni = 0; ni < 4; ni++) {
        int row = wn * 64 + ni * 16 + li;
        int cb = (lg * 16 + ks * 64) ^ ((row & 7) << 4);
        bfh[ni] = *(const f16x8*)((char*)Bs0 + row * 128 + cb);
        bfl[ni] = *(const f16x8*)((char*)Bs1 + row * 128 + cb);
      }
#pragma unroll
      for (int mi = 0; mi < 4; mi++)
#pragma unroll
        for (int ni = 0; ni < 4; ni++) {
          accA[mi][ni] = MFMAH(afh[mi], bfh[ni], accA[mi][ni]);
          accB[mi][ni] = MFMAH(afh[mi], bfl[ni], accB[mi][ni]);
          accB[mi][ni] = MFMAH(afl[mi], bfh[ni], accB[mi][ni]);
        }
    }
    __syncthreads();
  }
#pragma unroll
  for (int mi = 0; mi < 4; mi++)
#pragma unroll
    for (int ni = 0; ni < 4; ni++)
#pragma unroll
      for (int r = 0; r < 4; r++) {
        size_t m = m0 + wm * 64 + mi * 16 + lg * 4 + r;
        int c = n0 + wn * 64 + ni * 16 + li;
        C[m * (size_t)N + c] = accA[mi][ni][r] + accB[mi][ni][r] * C11 + bias[c];
      }
}

__device__ void dev_gemm_vf16(
    const f16* __restrict__ A, const f16* __restrict__ Bt,
    const float* __restrict__ bias, f16* __restrict__ Cout, int N, int K,
    int vb, f16* sh) {
  f16* Al = sh;
  f16* Bl = sh + 8192;
  int tid = threadIdx.x;
  int w = tid >> 6, lane = tid & 63;
  int lg = lane >> 4, li = lane & 15;
  size_t arow0 = (size_t)(vb >> 2) * 128;
  int n0 = (vb & 3) * 128;

  int rowA[4], scA[4];
#pragma unroll
  for (int j = 0; j < 4; j++) {
    int o = w * 4096 + j * 1024 + lane * 16;
    rowA[j] = o >> 7;
    scA[j] = ((o >> 4) & 7) ^ (rowA[j] & 7);
  }
  int wm = w >> 1, wn = w & 1;
  f32x4 acc[4][4] = {};

  for (int k0 = 0; k0 < K; k0 += 64) {
#pragma unroll
    for (int j = 0; j < 4; j++) {
      int o = w * 4096 + j * 1024 + lane * 16;
      gload16(A + (arow0 + rowA[j]) * (size_t)K + k0 + scA[j] * 8, (char*)Al + o);
      gload16(Bt + (size_t)(n0 + rowA[j]) * K + k0 + scA[j] * 8, (char*)Bl + o);
    }
    __syncthreads();
#pragma unroll
    for (int ks = 0; ks < 2; ks++) {
      f16x8 af[4], bfr[4];
#pragma unroll
      for (int mi = 0; mi < 4; mi++) {
        int row = wm * 64 + mi * 16 + li;
        int cb = (lg * 16 + ks * 64) ^ ((row & 7) << 4);
        af[mi] = *(const f16x8*)((char*)Al + row * 128 + cb);
      }
#pragma unroll
      for (int ni = 0; ni < 4; ni++) {
        int row = wn * 64 + ni * 16 + li;
        int cb = (lg * 16 + ks * 64) ^ ((row & 7) << 4);
        bfr[ni] = *(const f16x8*)((char*)Bl + row * 128 + cb);
      }
#pragma unroll
      for (int mi = 0; mi < 4; mi++)
#pragma unroll
        for (int ni = 0; ni < 4; ni++)
          acc[mi][ni] = MFMAH(af[mi], bfr[ni], acc[mi][ni]);
    }
    __syncthreads();
  }
#pragma unroll
  for (int mi = 0; mi < 4; mi++)
#pragma unroll
    for (int ni = 0; ni < 4; ni++)
#pragma unroll
      for (int r = 0; r < 4; r++) {
        size_t m = arow0 + wm * 64 + mi * 16 + lg * 4 + r;
        int c = n0 + wn * 64 + ni * 16 + li;
        Cout[m * (size_t)N + c] = (f16)(acc[mi][ni][r] + bias[c]);
      }
}

__global__ __launch_bounds__(256) void gemm_qv(
    const f16* __restrict__ Ah, const f16* __restrict__ Als,
    const f16* __restrict__ Bh, const f16* __restrict__ Bls,
    const float* __restrict__ bfull, float* __restrict__ qku32,
    const f16* __restrict__ Wvh, const float* __restrict__ bv,
    f16* __restrict__ vbuf) {
  __shared__ f16 sh[4 * 128 * 64];
  int bid = blockIdx.x;
  if (bid < 576)
    dev_gemm_split2(Ah, Als, Bh, Bls, bfull, qku32, NQKU_, D_, bid, sh);
  else
    dev_gemm_vf16(Ah, Wvh, bv, vbuf, D_, D_, bid - 576, sh);
}

// ===========================================================================
// prep_e: ksplit + transpose_u + xwg + transpose_v.  grid 8576 x 256.
// ===========================================================================
__global__ __launch_bounds__(256) void prep_e(
    const float* __restrict__ qku, unsigned short* __restrict__ kh,
    unsigned short* __restrict__ kls, f16* __restrict__ U2T,
    const float* __restrict__ x, const float* __restrict__ bo,
    const float* __restrict__ Wg, float* __restrict__ logits,
    const unsigned short* __restrict__ vbuf, unsigned short* __restrict__ vT) {
  __shared__ float smem[64 * 132];
  int bid = blockIdx.x;
  if (bid < 4096) { dev_ksplit(qku, kh, kls, bid); return; }
  bid -= 4096;
  if (bid < 128) { dev_transpose_u(qku, U2T, bid & 31, bid >> 5, smem); return; }
  bid -= 128;
  if (bid < 256) { dev_xwg(x, bo, Wg, logits, bid); return; }
  bid -= 256;
  dev_transpose_v(vbuf, vT, bid, (unsigned short*)smem);
}

// ---------------------------------------------------------------------------
// MFMA GEMM NT bf16 (FFN). 128x128 tile, BK=64, 256 thr.
// MODE 2: FFN1 (LeakyReLU, out bf16)  MODE 3: FFN2 (bias, out bf16)
// ---------------------------------------------------------------------------
template <int MODE>
__global__ __launch_bounds__(256) void gemm_mfma(
    const bf16* __restrict__ A, const bf16* __restrict__ Bt,
    const float* __restrict__ bias, const float* __restrict__ resid,
    void* __restrict__ Cout, int N, int K,
    const int* __restrict__ ebase, const int* __restrict__ ecnt) {
  __shared__ bf16 Al[128 * 64];
  __shared__ bf16 Bl[128 * 64];
  int tid = threadIdx.x;
  int w = tid >> 6, lane = tid & 63;
  int lg = lane >> 4, li = lane & 15;
  int e = 0;
  size_t arow0;
  if constexpr (MODE >= 2) {
    e = blockIdx.z;
    int r0 = blockIdx.y * 128;
    if (r0 >= ecnt[e]) return;
    arow0 = (size_t)(ebase[e] + r0);
  } else {
    arow0 = (size_t)blockIdx.y * 128;
  }
  int n0 = blockIdx.x * 128;
  const bf16* Bexp = Bt + (size_t)e * N * K;

  int rowA[4], scA[4];
#pragma unroll
  for (int j = 0; j < 4; j++) {
    int o = w * 4096 + j * 1024 + lane * 16;
    rowA[j] = o >> 7;
    scA[j] = ((o >> 4) & 7) ^ (rowA[j] & 7);
  }
  int wm = w >> 1, wn = w & 1;
  f32x4 acc[4][4] = {};

  for (int k0 = 0; k0 < K; k0 += 64) {
#pragma unroll
    for (int j = 0; j < 4; j++) {
      int o = w * 4096 + j * 1024 + lane * 16;
      gload16(A + (arow0 + rowA[j]) * (size_t)K + k0 + scA[j] * 8, (char*)Al + o);
      gload16(Bexp + (size_t)(n0 + rowA[j]) * K + k0 + scA[j] * 8, (char*)Bl + o);
    }
    __syncthreads();
#pragma unroll
    for (int ks = 0; ks < 2; ks++) {
      bf16x8 af[4], bfr[4];
#pragma unroll
      for (int mi = 0; mi < 4; mi++) {
        int row = wm * 64 + mi * 16 + li;
        int cb = (lg * 16 + ks * 64) ^ ((row & 7) << 4);
        af[mi] = *(const bf16x8*)((char*)Al + row * 128 + cb);
      }
#pragma unroll
      for (int ni = 0; ni < 4; ni++) {
        int row = wn * 64 + ni * 16 + li;
        int cb = (lg * 16 + ks * 64) ^ ((row & 7) << 4);
        bfr[ni] = *(const bf16x8*)((char*)Bl + row * 128 + cb);
      }
#pragma unroll
      for (int mi = 0; mi < 4; mi++)
#pragma unroll
        for (int ni = 0; ni < 4; ni++)
          acc[mi][ni] = MFMA16(af[mi], bfr[ni], acc[mi][ni]);
    }
    __syncthreads();
  }

#pragma unroll
  for (int mi = 0; mi < 4; mi++) {
#pragma unroll
    for (int ni = 0; ni < 4; ni++) {
#pragma unroll
      for (int r = 0; r < 4; r++) {
        size_t m = arow0 + wm * 64 + mi * 16 + lg * 4 + r;
        int c = n0 + wn * 64 + ni * 16 + li;
        float v = acc[mi][ni][r];
        if constexpr (MODE == 2) {
          if (c < HID_) {
            v += bias[e * HID_ + c];
            v = (v > 0.f) ? v : 0.01f * v;
            ((bf16*)Cout)[m * (size_t)HIDP_ + c] = __float2bfloat16(v);
          } else {
            ((bf16*)Cout)[m * (size_t)HIDP_ + c] = __float2bfloat16(0.f);
          }
        } else {
          v += bias[e * D_ + c];
          ((bf16*)Cout)[m * (size_t)N + c] = __float2bfloat16(v);
        }
      }
    }
  }
}

// ===========================================================================
// wo_rg: Wo-projection GEMM (bias+resid, out fp32) + reduce_gate fused.
// grid 288 x 256.
// ===========================================================================
__device__ void dev_gemm_wo(
    const bf16* __restrict__ A, const bf16* __restrict__ Bt,
    const float* __restrict__ bias, const float* __restrict__ resid,
    float* __restrict__ Cout, int vb, bf16* sh) {
  bf16* Al = sh;
  bf16* Bl = sh + 8192;
  const int N = D_, K = D_;
  int tid = threadIdx.x;
  int w = tid >> 6, lane = tid & 63;
  int lg = lane >> 4, li = lane & 15;
  size_t arow0 = (size_t)(vb >> 2) * 128;
  int n0 = (vb & 3) * 128;

  int rowA[4], scA[4];
#pragma unroll
  for (int j = 0; j < 4; j++) {
    int o = w * 4096 + j * 1024 + lane * 16;
    rowA[j] = o >> 7;
    scA[j] = ((o >> 4) & 7) ^ (rowA[j] & 7);
  }
  int wm = w >> 1, wn = w & 1;
  f32x4 acc[4][4] = {};

  for (int k0 = 0; k0 < K; k0 += 64) {
#pragma unroll
    for (int j = 0; j < 4; j++) {
      int o = w * 4096 + j * 1024 + lane * 16;
      gload16(A + (arow0 + rowA[j]) * (size_t)K + k0 + scA[j] * 8, (char*)Al + o);
      gload16(Bt + (size_t)(n0 + rowA[j]) * K + k0 + scA[j] * 8, (char*)Bl + o);
    }
    __syncthreads();
#pragma unroll
    for (int ks = 0; ks < 2; ks++) {
      bf16x8 af[4], bfr[4];
#pragma unroll
      for (int mi = 0; mi < 4; mi++) {
        int row = wm * 64 + mi * 16 + li;
        int cb = (lg * 16 + ks * 64) ^ ((row & 7) << 4);
        af[mi] = *(const bf16x8*)((char*)Al + row * 128 + cb);
      }
#pragma unroll
      for (int ni = 0; ni < 4; ni++) {
        int row = wn * 64 + ni * 16 + li;
        int cb = (lg * 16 + ks * 64) ^ ((row & 7) << 4);
        bfr[ni] = *(const bf16x8*)((char*)Bl + row * 128 + cb);
      }
#pragma unroll
      for (int mi = 0; mi < 4; mi++)
#pragma unroll
        for (int ni = 0; ni < 4; ni++)
          acc[mi][ni] = MFMA16(af[mi], bfr[ni], acc[mi][ni]);
    }
    __syncthreads();
  }
#pragma unroll
  for (int mi = 0; mi < 4; mi++)
#pragma unroll
    for (int ni = 0; ni < 4; ni++)
#pragma unroll
      for (int r = 0; r < 4; r++) {
        size_t m = arow0 + wm * 64 + mi * 16 + lg * 4 + r;
        int c = n0 + wn * 64 + ni * 16 + li;
        Cout[m * (size_t)N + c] = acc[mi][ni][r] + bias[c] + resid[m * (size_t)N + c];
      }
}

__device__ void dev_reduce_gate(
    const float* __restrict__ xwg, const float* __restrict__ part,
    int* __restrict__ e1a, int* __restrict__ e2a,
    float* __restrict__ g1a, float* __restrict__ g2a, int* __restrict__ use2a,
    float* __restrict__ dacc, int vb) {
  int t = vb * 256 + threadIdx.x;
  int b = t >> 11, s = t & 2047;
  float lg[8];
#pragma unroll
  for (int e = 0; e < 8; e++) lg[e] = xwg[(size_t)t * 8 + e];
  for (int h = 0; h < 8; h++) {
    const float* pp = part + ((size_t)(b * 8 + h) * S_ + s) * 8;
#pragma unroll
    for (int e = 0; e < 8; e++) lg[e] += pp[e];
  }
  float mx = lg[0];
#pragma unroll
  for (int e = 1; e < 8; e++) mx = fmaxf(mx, lg[e]);
  float p[8], se = 0.f;
#pragma unroll
  for (int e = 0; e < 8; e++) { p[e] = expf(lg[e] - mx); se += p[e]; }
  float inv = 1.f / se;
#pragma unroll
  for (int e = 0; e < 8; e++) p[e] *= inv;
  float lse = logf(se) + mx;
  int a1 = 0; float m1 = p[0];
#pragma unroll
  for (int e = 1; e < 8; e++) if (p[e] > m1) { m1 = p[e]; a1 = e; }
  int a2 = -1; float m2 = -1.f;
#pragma unroll
  for (int e = 0; e < 8; e++) if (e != a1 && p[e] > m2) { m2 = p[e]; a2 = e; }
  e1a[t] = a1; e2a[t] = a2; g1a[t] = m1; g2a[t] = m2;
  use2a[t] = (m2 > 0.2f) ? 1 : 0;
  float z = lse * lse;
  float pr[8];
#pragma unroll
  for (int e = 0; e < 8; e++) pr[e] = p[e];
#pragma unroll
  for (int off = 1; off < 64; off <<= 1) {
#pragma unroll
    for (int e = 0; e < 8; e++) pr[e] += __shfl_xor(pr[e], off);
    z += __shfl_xor(z, off);
  }
  float dcnt[8];
#pragma unroll
  for (int e = 0; e < 8; e++) dcnt[e] = (float)__popcll(__ballot(a1 == e));
  if ((threadIdx.x & 63) == 0) {
#pragma unroll
    for (int e = 0; e < 8; e++) {
      atomicAdd(&dacc[e], dcnt[e]);
      atomicAdd(&dacc[8 + e], pr[e]);
    }
    atomicAdd(&dacc[16], z);
  }
}

__global__ __launch_bounds__(256) void wo_rg(
    const bf16* __restrict__ attnb, const bf16* __restrict__ Wob,
    const float* __restrict__ bo, const float* __restrict__ x,
    float* __restrict__ o2,
    const float* __restrict__ xwg, const float* __restrict__ part,
    int* __restrict__ e1a, int* __restrict__ e2a,
    float* __restrict__ g1a, float* __restrict__ g2a, int* __restrict__ use2a,
    float* __restrict__ dacc) {
  __shared__ bf16 sh[2 * 128 * 64];
  int bid = blockIdx.x;
  if (bid < 256) dev_gemm_wo(attnb, Wob, bo, x, o2, bid, sh);
  else dev_reduce_gate(xwg, part, e1a, e2a, g1a, g2a, use2a, dacc, bid - 256);
}

// ---------------------------------------------------------------------------
// attn_fused (fp16 split-2): 4-wave blocks, 64 q-rows, KV tile 64.
// (round-16 body — measured best)
// ---------------------------------------------------------------------------
__global__ __launch_bounds__(256, 4) void attn_fused(
    const float* __restrict__ qku,
    const f16* __restrict__ kh, const f16* __restrict__ kls,
    const f16* __restrict__ vT, const f16* __restrict__ U2T,
    bf16* __restrict__ attnb, float* __restrict__ part) {
  __shared__ f16 Ks0[64 * 64];
  __shared__ f16 Ks1[64 * 64];
  __shared__ f16 Vtl[64 * 64];      // [d][key]
  __shared__ f16 Ut[16 * 64];       // rows 0..7 = U-hi[e], rows 8..15 = U-lo*2048
  __shared__ f16 Pl[4][16 * 40];    // per-wave P, 16 q x 32 keys, stride 80B
  int bid = blockIdx.x;
  int xcd = bid & 7, idx = bid >> 3; // idx 0..127
  int bh = (idx >> 5) * 8 + xcd;     // b = idx>>5, h = xcd
  int qt = idx & 31;
  int b = bh >> 3, h = bh & 7, q0 = qt * 64;
  int tid = threadIdx.x, w = tid >> 6, lane = tid & 63;
  int lg = lane >> 4, qi = lane & 15;
  const float KS = 0.125f * 1.44269504089f;   // exp2 domain
  const float KS2 = KS * C11;

  // q split-2 in-register (hi + lo*2048)
  const float* qsrc = qku + (size_t)(b * S_ + q0 + w * 16 + qi) * NQKU_ + h * 64 + lg * 8;
  f16x8 qh[2], qls[2];
#pragma unroll
  for (int ks = 0; ks < 2; ks++) {
#pragma unroll
    for (int i = 0; i < 8; i++) {
      float xv = qsrc[ks * 32 + i];
      f16 hh = (f16)xv;
      f16 ll = (f16)((xv - (float)hh) * 2048.f);
      qh[ks][i] = hh;
      qls[ks][i] = ll;
    }
  }

  f32x4 oacc[4] = {};
  f32x4 raccA = {0.f, 0.f, 0.f, 0.f};
  f32x4 raccB = {0.f, 0.f, 0.f, 0.f};
  float mrun = -1e30f, lrun = 0.f;
  const f16* Vbase = vT + (size_t)bh * DH_ * S_;
  char* pw = (char*)&Pl[w][0];

  for (int kt = 0; kt < S_ / 64; kt++) {
    // stage K splits (8KB each) + V tile (8KB) across 4 waves; U (2KB) w<2
#pragma unroll
    for (int j = 0; j < 2; j++) {
      int o = w * 2048 + j * 1024 + lane * 16;
      int row = o >> 7;                       // 0..63
      int sc = ((o >> 4) & 7) ^ (row & 7);
      size_t srcK = ((size_t)bh * S_ + kt * 64 + row) * 64 + sc * 8;
      gload16(kh + srcK, (char*)Ks0 + o);
      gload16(kls + srcK, (char*)Ks1 + o);
      gload16(Vbase + (size_t)row * S_ + kt * 64 + sc * 8, (char*)Vtl + o);
    }
    if (w < 2) {
      int o = w * 1024 + lane * 16;
      int rowu = o >> 7;                      // 0..15
      int scu = ((o >> 4) & 7) ^ (rowu & 7);
      gload16(U2T + ((size_t)(bh * 16 + rowu) * 2048 + kt * 64 + scu * 8),
              (char*)Ut + o);
    }
    __syncthreads();

    // precise scores: 3-product fp16 split-2; lo accumulator is nb-local.
    f32x4 sA[4];
    float tmax = -1e30f;
#pragma unroll
    for (int nb = 0; nb < 4; nb++) {
      f32x4 a = {0.f, 0.f, 0.f, 0.f};
      f32x4 bq = {0.f, 0.f, 0.f, 0.f};
      int row = nb * 16 + qi;
#pragma unroll
      for (int ks = 0; ks < 2; ks++) {
        int cb = (lg * 16 + ks * 64) ^ ((row & 7) << 4);
        f16x8 k0 = *(const f16x8*)((char*)Ks0 + row * 128 + cb);
        f16x8 k1 = *(const f16x8*)((char*)Ks1 + row * 128 + cb);
        a = MFMAH(k0, qh[ks], a);
        bq = MFMAH(k0, qls[ks], bq);
        bq = MFMAH(k1, qh[ks], bq);
      }
#pragma unroll
      for (int r = 0; r < 4; r++) {
        float v = a[r] * KS + bq[r] * KS2;
        sA[nb][r] = v;
        tmax = fmaxf(tmax, v);
      }
    }
    // online softmax with defer-max (THR=8 log2)
    tmax = fmaxf(tmax, __shfl_xor(tmax, 16));
    tmax = fmaxf(tmax, __shfl_xor(tmax, 32));
    float fsc = 1.f;
    if (!__all(tmax <= mrun + 8.f)) {
      float mnew = fmaxf(mrun, tmax);
      fsc = exp2f(mrun - mnew);
      mrun = mnew;
#pragma unroll
      for (int r = 0; r < 4; r++) { raccA[r] *= fsc; raccB[r] *= fsc; }
#pragma unroll
      for (int db = 0; db < 4; db++)
#pragma unroll
        for (int r = 0; r < 4; r++) oacc[db][r] *= fsc;
    }
    float psum = 0.f;
#pragma unroll
    for (int nb = 0; nb < 4; nb++)
#pragma unroll
      for (int r = 0; r < 4; r++) {
        float pv = exp2f(sA[nb][r] - mrun);
        sA[nb][r] = pv;
        psum += pv;
      }
    psum += __shfl_xor(psum, 16);
    psum += __shfl_xor(psum, 32);
    lrun = lrun * fsc + psum;

    // per 32-key chunk (c=0,1): write P hi -> PV + P.U; write P lo -> P.U
#pragma unroll
    for (int c = 0; c < 2; c++) {
#pragma unroll
      for (int nbL = 0; nbL < 2; nbL++)
#pragma unroll
        for (int rp = 0; rp < 2; rp++) {
          int nb = c * 2 + nbL;
          float p0 = sA[nb][rp * 2], p1 = sA[nb][rp * 2 + 1];
          h16x2 hp = __builtin_amdgcn_cvt_pkrtz(p0, p1);
          int keyl = 4 * lg + 2 * rp + 16 * nbL;
          *(unsigned*)(pw + qi * 80 + keyl * 2) = *(unsigned*)&hp;
        }
      f16x8 pf = *(const f16x8*)(pw + qi * 80 + lg * 16);
#pragma unroll
      for (int db = 0; db < 4; db++) {
        int row = db * 16 + qi;
        int cb = (lg * 16 + c * 64) ^ ((row & 7) << 4);
        f16x8 vf = *(const f16x8*)((char*)Vtl + row * 128 + cb);
        oacc[db] = MFMAH(vf, pf, oacc[db]);
      }
      int ua = qi * 128 + ((c * 64 + lg * 16) ^ ((qi & 7) << 4));
      f16x8 uf = *(const f16x8*)((char*)Ut + ua);
      raccA = MFMAH(uf, pf, raccA);
      // P lo into the same slot (wave LDS ops in order: pf read drains first)
#pragma unroll
      for (int nbL = 0; nbL < 2; nbL++)
#pragma unroll
        for (int rp = 0; rp < 2; rp++) {
          int nb = c * 2 + nbL;
          float p0 = sA[nb][rp * 2], p1 = sA[nb][rp * 2 + 1];
          h16x2 hp = __builtin_amdgcn_cvt_pkrtz(p0, p1);
          float b0 = (float)hp[0], b1 = (float)hp[1];
          h16x2 lp = __builtin_amdgcn_cvt_pkrtz((p0 - b0) * 2048.f, (p1 - b1) * 2048.f);
          int keyl = 4 * lg + 2 * rp + 16 * nbL;
          *(unsigned*)(pw + qi * 80 + keyl * 2) = *(unsigned*)&lp;
        }
      f16x8 pfl = *(const f16x8*)(pw + qi * 80 + lg * 16);
      raccB = MFMAH(uf, pfl, raccB);
    }
    __syncthreads();
  }

  float inv = 1.f / lrun;
  // routing epilogue:
  // raccA(lg<2)=Uh.Ph, raccA(lg>=2)=Uls.Ph, raccB(lg<2)=Uh.Pls, raccB(lg>=2)=Uls.Pls
  f32x4 pA, pB;
#pragma unroll
  for (int r = 0; r < 4; r++) {
    pA[r] = __shfl_xor(raccA[r], 32);
    pB[r] = __shfl_xor(raccB[r], 32);
  }
  if (lg < 2) {
    float* dst = part + ((size_t)bh * S_ + q0 + w * 16 + qi) * 8 + lg * 4;
#pragma unroll
    for (int r = 0; r < 4; r++)
      dst[r] = (raccA[r] + C11 * (pA[r] + raccB[r]) + C22 * pB[r]) * inv;
  }
  // value epilogue: O^T -> O via wave-private 2KB scratch in Ks0
  char* ow = (char*)Ks0 + w * 2048;
#pragma unroll
  for (int db = 0; db < 4; db++)
#pragma unroll
    for (int rp = 0; rp < 2; rp++) {
      int d = db * 16 + lg * 4 + rp * 2;
      unsigned pk = bf16pk(oacc[db][rp * 2] * inv, oacc[db][rp * 2 + 1] * inv);
      int addr = (qi * 128 + d * 2) ^ ((qi & 7) << 4);
      *(unsigned*)(ow + addr) = pk;
    }
#pragma unroll
  for (int j = 0; j < 2; j++) {
    int o = j * 1024 + lane * 16;
    int q = o >> 7;
    int c16 = (o >> 4) & 7;
    int sc = c16 ^ (q & 7);
    bf16x8 vv = *(const bf16x8*)(ow + q * 128 + sc * 16);
    *(bf16x8*)(attnb + ((size_t)(b * S_ + q0 + w * 16 + q)) * D_ + h * DH_ + c16 * 8) = vv;
  }
}

// ---------------------------------------------------------------------------
// Capacity scan: exact cumsum order, parallelized (8 waves, 2-pass).
// ---------------------------------------------------------------------------
__global__ __launch_bounds__(512) void scan_kernel(
    const int* __restrict__ e1a, const int* __restrict__ e2a,
    const int* __restrict__ use2a,
    int* __restrict__ posArr, int* __restrict__ kept_be) {
  __shared__ int wcnt[8][8];
  int b = blockIdx.x;
  int w = threadIdx.x >> 6, lane = threadIdx.x & 63;
  unsigned long long below = (1ull << lane) - 1ull;
  int cnt[8] = {0, 0, 0, 0, 0, 0, 0, 0};
  int ev[8], av[8];
#pragma unroll
  for (int it = 0; it < 8; it++) {
    int i = w * 512 + it * 64 + lane;
    int s = i & (S_ - 1);
    int t = b * S_ + s;
    int e, a;
    if (i < S_) { e = e1a[t]; a = 1; }
    else        { e = e2a[t]; a = use2a[t]; }
    ev[it] = e; av[it] = a;
#pragma unroll
    for (int ee = 0; ee < 8; ee++)
      cnt[ee] += __popcll(__ballot(a && (e == ee)));
  }
  if (lane == 0)
#pragma unroll
    for (int ee = 0; ee < 8; ee++) wcnt[w][ee] = cnt[ee];
  __syncthreads();
  int run[8];
#pragma unroll
  for (int ee = 0; ee < 8; ee++) {
    int sB = 0;
    for (int ww = 0; ww < w; ww++) sB += wcnt[ww][ee];
    run[ee] = sB;
  }
#pragma unroll
  for (int it = 0; it < 8; it++) {
    int i = w * 512 + it * 64 + lane;
    int e = ev[it], a = av[it];
    int pos = -1;
#pragma unroll
    for (int ee = 0; ee < 8; ee++) {
      unsigned long long mask = __ballot(a && (e == ee));
      if (a && e == ee) pos = run[ee] + __popcll(mask & below);
      run[ee] += __popcll(mask);
    }
    posArr[b * (2 * S_) + i] = (a && pos < CAP_) ? pos : -1;
  }
  if (w == 7 && lane == 0)
#pragma unroll
    for (int ee = 0; ee < 8; ee++) kept_be[b * 8 + ee] = min(run[ee], CAP_);
}

// ---------------------------------------------------------------------------
// Meta: 128-aligned per-expert bases + aux-loss scalars.
// ---------------------------------------------------------------------------
__global__ void finalize_meta(const int* __restrict__ kept_be,
                              int* __restrict__ ebase, int* __restrict__ bbase,
                              int* __restrict__ ecnt,
                              const float* __restrict__ dacc, float* __restrict__ outs) {
  if (threadIdx.x == 0 && blockIdx.x == 0) {
    int base = 0;
    for (int e = 0; e < 8; e++) {
      int tot = 0;
      for (int b = 0; b < 4; b++) { bbase[b * 8 + e] = tot; tot += kept_be[b * 8 + e]; }
      ecnt[e] = tot;
      ebase[e] = base;
      base += (tot + 127) & ~127;
    }
    float bal = 0.f;
    for (int e = 0; e < 8; e++) bal += (dacc[e] / (float)TOK_) * (dacc[8 + e] / (float)TOK_);
    bal *= (float)E_;
    float z = dacc[16] / (float)TOK_;
    outs[0] = 0.01f * bal + 0.001f * z;
    outs[1] = bal;
    outs[2] = z;
  }
}

// ---------------------------------------------------------------------------
// Scatter: compacted row lists + per-token combine info.
// ---------------------------------------------------------------------------
__global__ __launch_bounds__(256) void scatter_kernel(
    const int* __restrict__ posArr, const int* __restrict__ e1a, const int* __restrict__ e2a,
    const float* __restrict__ g1a, const float* __restrict__ g2a,
    const int* __restrict__ ebase, const int* __restrict__ bbase,
    int* __restrict__ rowtok, int* __restrict__ rowexp,
    int* __restrict__ tokidx, float* __restrict__ tokw) {
  int gi = blockIdx.x * 256 + threadIdx.x;
  int b = gi >> 12, i = gi & 4095;
  int k = i >> 11, s = i & (S_ - 1);
  int t = b * S_ + s;
  int pos = posArr[gi];
  int idx = -1; float w = 0.f;
  if (pos >= 0) {
    int e = k ? e2a[t] : e1a[t];
    idx = ebase[e] + bbase[b * 8 + e] + pos;
    rowtok[idx] = t;
    rowexp[idx] = e;
    w = k ? g2a[t] : g1a[t];
  }
  tokidx[k * TOK_ + t] = idx;
  tokw[k * TOK_ + t] = w;
}

// ---------------------------------------------------------------------------
// LayerNorm per compacted row -> bf16.
// ---------------------------------------------------------------------------
__global__ __launch_bounds__(256) void ln_kernel(
    const float* __restrict__ o2, const int* __restrict__ rowtok,
    const int* __restrict__ rowexp, const float* __restrict__ ln_g,
    const float* __restrict__ ln_b, bf16* __restrict__ xn) {
  int row = blockIdx.x * 4 + (threadIdx.x >> 6);
  int lane = threadIdx.x & 63;
  int tok = rowtok[row];
  if (tok < 0) return;
  int e = rowexp[row];
  const float* xr = o2 + (size_t)tok * D_;
  float v[8], sum = 0.f, sq = 0.f;
#pragma unroll
  for (int j = 0; j < 8; j++) { v[j] = xr[lane * 8 + j]; sum += v[j]; sq += v[j] * v[j]; }
#pragma unroll
  for (int off = 1; off < 64; off <<= 1) { sum += __shfl_xor(sum, off); sq += __shfl_xor(sq, off); }
  float mu = sum / (float)D_;
  float var = sq / (float)D_ - mu * mu;
  float inv = rsqrtf(var + 1e-5f);
  bf16* xo = xn + (size_t)row * D_;
#pragma unroll
  for (int j = 0; j < 8; j++) {
    int d = lane * 8 + j;
    xo[d] = __float2bfloat16((v[j] - mu) * inv * ln_g[e * D_ + d] + ln_b[e * D_ + d]);
  }
}

// ---------------------------------------------------------------------------
// Combine: out = o2 + w1*y[idx1] + w2*y[idx2]   (y bf16)
// ---------------------------------------------------------------------------
__global__ __launch_bounds__(256) void combine_kernel(
    const float* __restrict__ o2, const bf16* __restrict__ y,
    const int* __restrict__ tokidx, const float* __restrict__ tokw,
    float* __restrict__ out) {
  size_t gi = (size_t)blockIdx.x * 256 + threadIdx.x;
  int t = (int)(gi >> 9);
  int d = (int)(gi & (D_ - 1));
  float v = o2[gi];
  int i1 = tokidx[t], i2 = tokidx[TOK_ + t];
  if (i1 >= 0) v += tokw[t] * __bfloat162float(y[(size_t)i1 * D_ + d]);
  if (i2 >= 0) v += tokw[TOK_ + t] * __bfloat162float(y[(size_t)i2 * D_ + d]);
  out[gi] = v;
}

// ---------------------------------------------------------------------------
extern "C" void kernel_launch(void* const* d_in, const int* in_sizes, int n_in,
                              void* d_out, int out_size, void* d_ws, size_t ws_size,
                              hipStream_t stream) {
  const float* x    = (const float*)d_in[0];
  const float* Wqkv = (const float*)d_in[1];
  const float* bqkv = (const float*)d_in[2];
  const float* Wo   = (const float*)d_in[3];
  const float* bo   = (const float*)d_in[4];
  const float* Wg   = (const float*)d_in[5];
  const float* ln_g = (const float*)d_in[6];
  const float* ln_b = (const float*)d_in[7];
  const float* W1   = (const float*)d_in[8];
  const float* b1   = (const float*)d_in[9];
  const float* W2   = (const float*)d_in[10];
  const float* b2   = (const float*)d_in[11];
  float* out = (float*)d_out;

  char* ws = (char*)d_ws;
  size_t off = 0;
  auto alloc = [&](size_t bytes) -> void* {
    void* p = ws + off;
    off = (off + bytes + 255) & ~(size_t)255;
    return p;
  };
  float* qku32 = (float*)alloc((size_t)TOK_ * NQKU_ * 4); // 37.7 MB
  f16*  vbuf   = (f16*)alloc((size_t)TOK_ * D_ * 2);
  f16*  vT     = (f16*)alloc((size_t)B_ * H_ * DH_ * S_ * 2);
  bf16* attnb  = (bf16*)alloc((size_t)TOK_ * D_ * 2);
  float* o2    = (float*)alloc((size_t)TOK_ * D_ * 4);
  f16*  xh     = (f16*)alloc((size_t)TOK_ * D_ * 2);
  f16*  xls    = (f16*)alloc((size_t)TOK_ * D_ * 2);
  f16*  Wqh    = (f16*)alloc((size_t)NQKU_ * D_ * 2);
  f16*  Wqls   = (f16*)alloc((size_t)NQKU_ * D_ * 2);
  f16*  Wvh    = (f16*)alloc((size_t)D_ * D_ * 2);
  bf16* Wob    = (bf16*)alloc((size_t)D_ * D_ * 2);
  bf16* W1t    = (bf16*)alloc((size_t)E_ * HIDP_ * D_ * 2);
  bf16* W2t    = (bf16*)alloc((size_t)E_ * D_ * HIDP_ * 2);
  bf16* xn     = (bf16*)alloc((size_t)RMAX_ * D_ * 2);
  bf16* hbuf   = (bf16*)alloc((size_t)RMAX_ * HIDP_ * 2);
  bf16* ybuf   = (bf16*)alloc((size_t)RMAX_ * D_ * 2);
  float* Wg2   = (float*)alloc(D_ * E_ * 4);
  float* bfull = (float*)alloc(NQKU_ * 4);
  f16*  U2T    = (f16*)alloc((size_t)32 * 16 * 2048 * 2);
  float* logits= (float*)alloc((size_t)TOK_ * 8 * 4);
  float* part  = (float*)alloc((size_t)B_ * H_ * S_ * 8 * 4);
  int*   e1a   = (int*)alloc(TOK_ * 4);
  int*   e2a   = (int*)alloc(TOK_ * 4);
  int*   use2a = (int*)alloc(TOK_ * 4);
  float* g1a   = (float*)alloc(TOK_ * 4);
  float* g2a   = (float*)alloc(TOK_ * 4);
  int*   posArr  = (int*)alloc(NASS_ * 4);
  int*   kept_be = (int*)alloc(32 * 4);
  int*   ebase   = (int*)alloc(8 * 4);
  int*   bbase   = (int*)alloc(32 * 4);
  int*   ecnt    = (int*)alloc(8 * 4);
  int*   rowtok  = (int*)alloc(RMAX_ * 4);
  int*   rowexp  = (int*)alloc(RMAX_ * 4);
  int*   tokidx  = (int*)alloc(NASS_ * 4);
  float* tokw    = (float*)alloc(NASS_ * 4);
  float* dacc    = (float*)alloc(32 * 4);
  // kh/kls alias xh/xls (same size; prep_e runs after all consumers of xh/xls)
  f16* kh  = xh;
  f16* kls = xls;

  // 1. prep_a: memsets + all independent weight/input conversions
  prep_a<<<16469, 256, 0, stream>>>(x, Wqkv, Wo, W1, W2, Wg,
                                    (unsigned short*)xh, (unsigned short*)xls,
                                    (unsigned short*)Wqh, (unsigned short*)Wqls,
                                    Wvh, Wob, W1t, W2t, Wg2, rowtok, dacc);
  // 2. wu2: folded-gate weight rows + split-2 direct into Wqh/Wqls tail
  wu_kernel2<<<256, 256, 0, stream>>>(Wqkv, Wg2, bqkv,
      (unsigned short*)(Wqh + (size_t)1024 * D_),
      (unsigned short*)(Wqls + (size_t)1024 * D_), bfull);
  // 3. q,k,U split-2 GEMM + v GEMM in one launch
  gemm_qv<<<832, 256, 0, stream>>>(xh, xls, Wqh, Wqls, bfull, qku32,
                                   Wvh, bqkv + 1024, vbuf);
  // 4. routing/attention preps (kh/kls overwrite xh/xls — consumers done)
  prep_e<<<8576, 256, 0, stream>>>(qku32, (unsigned short*)kh,
                                   (unsigned short*)kls, U2T, x, bo, Wg,
                                   logits, (const unsigned short*)vbuf,
                                   (unsigned short*)vT);
  // 5. fused attention: value O + routing part in one pass
  attn_fused<<<dim3(1024), 256, 0, stream>>>(qku32, kh, kls, vT, U2T,
                                             attnb, part);
  // 6. Wo-projection GEMM + routing reduce in one launch
  wo_rg<<<288, 256, 0, stream>>>(attnb, Wob, bo, x, o2, logits, part,
                                 e1a, e2a, g1a, g2a, use2a, dacc);
  // 7-9. capacity scan, meta, scatter
  scan_kernel<<<B_, 512, 0, stream>>>(e1a, e2a, use2a, posArr, kept_be);
  finalize_meta<<<1, 64, 0, stream>>>(kept_be, ebase, bbase, ecnt, dacc,
                                      out + (size_t)TOK_ * D_);
  scatter_kernel<<<NASS_ / 256, 256, 0, stream>>>(posArr, e1a, e2a, g1a, g2a,
                                                  ebase, bbase, rowtok, rowexp,
                                                  tokidx, tokw);
  // 10. LayerNorm
  ln_kernel<<<RMAX_ / 4, 256, 0, stream>>>(o2, rowtok, rowexp, ln_g, ln_b, xn);
  // 11-12. expert FFN
  gemm_mfma<2><<<dim3(HIDP_ / 128, 32, E_), 256, 0, stream>>>(xn, W1t, b1, nullptr, hbuf,
                                                              HIDP_, D_, ebase, ecnt);
  gemm_mfma<3><<<dim3(D_ / 128, 32, E_), 256, 0, stream>>>(hbuf, W2t, b2, nullptr, ybuf,
                                                           D_, HIDP_, ebase, ecnt);
  // 13. combine
  combine_kernel<<<(TOK_ * D_) / 256, 256, 0, stream>>>(o2, ybuf, tokidx, tokw, out);
}

// Round 19
// 430.591 us; speedup vs baseline: 1.1047x; 1.0057x over previous
//
#include <hip/hip_runtime.h>
#include <hip/hip_bf16.h>
#include <math.h>

// Problem constants
#define B_    4
#define S_    2048
#define D_    512
#define H_    8
#define DH_   64
#define E_    8
#define HID_  1365
#define HIDP_ 1408
#define CAP_  1024
#define TOK_  (B_*S_)
#define NASS_ (B_*2*S_)
#define RMAX_ (NASS_ + 8*128)
#define NQKU_ 1152   // q(512) | k(512) | U(128)
#define C11   (1.0f/2048.0f)
#define C22   (1.0f/(2048.0f*2048.0f))

typedef __attribute__((ext_vector_type(8))) short bf16x8;
typedef __attribute__((ext_vector_type(8))) _Float16 f16x8;
typedef __attribute__((ext_vector_type(2))) __fp16 h16x2;   // cvt_pkrtz result type
typedef __attribute__((ext_vector_type(4))) float f32x4;
typedef __hip_bfloat16 bf16;
typedef _Float16 f16;

#define MFMA16(a, b, c) __builtin_amdgcn_mfma_f32_16x16x32_bf16(a, b, c, 0, 0, 0)
#define MFMAH(a, b, c)  __builtin_amdgcn_mfma_f32_16x16x32_f16(a, b, c, 0, 0, 0)

__device__ __forceinline__ void gload16(const void* g, void* l) {
  __builtin_amdgcn_global_load_lds(
      (const __attribute__((address_space(1))) unsigned int*)g,
      (__attribute__((address_space(3))) unsigned int*)l, 16, 0, 0);
}

__device__ __forceinline__ unsigned bf16pk(float a, float b) {
  unsigned ua = __float_as_uint(a); ua = (ua + 0x7FFF + ((ua >> 16) & 1)) >> 16;
  unsigned ub = __float_as_uint(b); ub = (ub + 0x7FFF + ((ub >> 16) & 1)) >> 16;
  return ua | (ub << 16);
}

__device__ __forceinline__ unsigned short h2us(f16 h) {
  return *(unsigned short*)&h;
}

// ===========================================================================
// Device bodies (virtual-block versions) for the fused prep kernels
// ===========================================================================

__device__ __forceinline__ void dev_split2h(const float* __restrict__ in,
    unsigned short* __restrict__ ph, unsigned short* __restrict__ pl,
    int n, int vb) {
  int i = (vb * 256 + threadIdx.x) * 4;
  if (i >= n) return;
  float4 v = *(const float4*)(in + i);
  float a[4] = {v.x, v.y, v.z, v.w};
  ushort4 hh, ll;
#pragma unroll
  for (int j = 0; j < 4; j++) {
    f16 h = (f16)a[j];
    float r = (a[j] - (float)h) * 2048.f;
    f16 l = (f16)r;
    ((unsigned short*)&hh)[j] = h2us(h);
    ((unsigned short*)&ll)[j] = h2us(l);
  }
  *(ushort4*)(ph + i) = hh;
  *(ushort4*)(pl + i) = ll;
}

__device__ __forceinline__ void dev_cvt_f16(const float* __restrict__ in,
                                            f16* __restrict__ out, int n, int vb) {
  int i = (vb * 256 + threadIdx.x) * 4;
  if (i >= n) return;
  float4 v = *(const float4*)(in + i);
  ushort4 o;
  ((unsigned short*)&o)[0] = h2us((f16)v.x);
  ((unsigned short*)&o)[1] = h2us((f16)v.y);
  ((unsigned short*)&o)[2] = h2us((f16)v.z);
  ((unsigned short*)&o)[3] = h2us((f16)v.w);
  *(ushort4*)((unsigned short*)out + i) = o;
}

__device__ __forceinline__ void dev_cvt_bf16(const float* __restrict__ in,
                                             bf16* __restrict__ out, int n, int vb) {
  int i = (vb * 256 + threadIdx.x) * 4;
  if (i >= n) return;
  float4 v = *(const float4*)(in + i);
  uint2 pk; pk.x = bf16pk(v.x, v.y); pk.y = bf16pk(v.z, v.w);
  *(uint2*)((unsigned short*)out + i) = pk;
}

// W1 [e][512][1365] -> W1t [e][1408][512] bf16 (zero pad). vb in [0, 5632)
__device__ __forceinline__ void dev_transpose_w1(const float* __restrict__ W1,
    bf16* __restrict__ W1t, int vb, float* sm) {
  int xg = vb % 44, yg = (vb / 44) % 16, e = vb / 704;
  int n0 = xg * 32, d0 = yg * 32;
  int tx = threadIdx.x & 31, ty = threadIdx.x >> 5;
  const float* in = W1 + (size_t)e * D_ * HID_;
  bf16* out = W1t + (size_t)e * HIDP_ * D_;
#pragma unroll
  for (int j = 0; j < 4; j++) {
    int d = d0 + ty + j * 8, n = n0 + tx;
    sm[(ty + j * 8) * 33 + tx] = (n < HID_) ? in[(size_t)d * HID_ + n] : 0.f;
  }
  __syncthreads();
#pragma unroll
  for (int j = 0; j < 4; j++) {
    int n = n0 + ty + j * 8, d = d0 + tx;
    out[(size_t)n * D_ + d] = __float2bfloat16(sm[tx * 33 + ty + j * 8]);
  }
}

// W2 [e][1365][512] -> W2t [e][512][1408] bf16 (zero pad). vb in [0, 5632)
__device__ __forceinline__ void dev_transpose_w2(const float* __restrict__ W2,
    bf16* __restrict__ W2t, int vb, float* sm) {
  int xg = vb % 16, yg = (vb / 16) % 44, e = vb / 704;
  int n0 = xg * 32, k0 = yg * 32;
  int tx = threadIdx.x & 31, ty = threadIdx.x >> 5;
  const float* in = W2 + (size_t)e * HID_ * D_;
  bf16* out = W2t + (size_t)e * D_ * HIDP_;
#pragma unroll
  for (int j = 0; j < 4; j++) {
    int k = k0 + ty + j * 8;
    sm[(ty + j * 8) * 33 + tx] = (k < HID_) ? in[(size_t)k * D_ + n0 + tx] : 0.f;
  }
  __syncthreads();
#pragma unroll
  for (int j = 0; j < 4; j++) {
    int n = n0 + ty + j * 8, k = k0 + tx;
    out[(size_t)n * HIDP_ + k] = __float2bfloat16(sm[tx * 33 + ty + j * 8]);
  }
}

// Wg2[d][e] = sum_n Wo[n][d] * Wg[n][e]. vb in [0,16)
__device__ __forceinline__ void dev_wg2(const float* __restrict__ Wo,
    const float* __restrict__ Wg, float* __restrict__ Wg2, int vb) {
  int gid = vb * 256 + threadIdx.x;
  int d = gid >> 3, e = gid & 7;
  float acc = 0.f;
  for (int n = 0; n < D_; n++) acc += Wo[(size_t)n * D_ + d] * Wg[n * E_ + e];
  Wg2[d * E_ + e] = acc;
}

// ksplit. vb in [0, 4096)
__device__ __forceinline__ void dev_ksplit(const float* __restrict__ qku,
    unsigned short* __restrict__ kh, unsigned short* __restrict__ kls, int vb) {
  int gid = vb * 256 + threadIdx.x;
  int idx4 = gid * 4;
  int t = idx4 >> 9, c = idx4 & 511;
  int h = c >> 6, d = c & 63;
  int b = t >> 11, s = t & 2047;
  float4 v = *(const float4*)(qku + (size_t)t * NQKU_ + 512 + c);
  float a[4] = {v.x, v.y, v.z, v.w};
  ushort4 hh, ll;
#pragma unroll
  for (int j = 0; j < 4; j++) {
    f16 hv = (f16)a[j];
    f16 lv = (f16)((a[j] - (float)hv) * 2048.f);
    ((unsigned short*)&hh)[j] = h2us(hv);
    ((unsigned short*)&ll)[j] = h2us(lv);
  }
  size_t o = (((size_t)(b * 8 + h) * S_ + s) * 64 + d);
  *(ushort4*)(kh + o) = hh;
  *(ushort4*)(kls + o) = ll;
}

// transpose_u. bx in [0,32), by in [0,4). Vectorized ushort4 stores.
__device__ __forceinline__ void dev_transpose_u(const float* __restrict__ qku,
    f16* __restrict__ U2T, int bx, int by, float* sm) {
  int b = by;
  int s0 = bx * 64;
  int tid = threadIdx.x;
#pragma unroll
  for (int p = 0; p < 8; p++) {
    int i = tid + p * 256;
    int tok = i >> 5, c4 = i & 31;
    float4 v = *(const float4*)(qku + (size_t)(b * 2048 + s0 + tok) * NQKU_ + 1024 + c4 * 4);
    sm[tok * 132 + c4 * 4 + 0] = v.x; sm[tok * 132 + c4 * 4 + 1] = v.y;
    sm[tok * 132 + c4 * 4 + 2] = v.z; sm[tok * 132 + c4 * 4 + 3] = v.w;
  }
  __syncthreads();
  int row = tid >> 1, sh = tid & 1;
  int h = row >> 4, rr = row & 15;
  int e = rr & 7;
  bool lo = rr >= 8;
  f16* dst = U2T + ((size_t)((b * 8 + h) * 16 + rr) * 2048 + s0 + sh * 32);
#pragma unroll
  for (int i = 0; i < 32; i += 4) {
    ushort4 o;
#pragma unroll
    for (int j = 0; j < 4; j++) {
      float v = sm[(sh * 32 + i + j) * 132 + h * 8 + e];
      f16 hh = (f16)v;
      f16 outv = lo ? (f16)((v - (float)hh) * 2048.f) : hh;
      ((unsigned short*)&o)[j] = h2us(outv);
    }
    *(ushort4*)(dst + i) = o;
  }
}

// xwg. vb in [0, 256)
__device__ __forceinline__ void dev_xwg(const float* __restrict__ x,
    const float* __restrict__ bo, const float* __restrict__ Wg,
    float* __restrict__ logits, int vb) {
  int tid = threadIdx.x;
  int tl = tid >> 3, j = tid & 7;
  int t = vb * 32 + tl;
  const float* xr = x + (size_t)t * D_;
  float part[8] = {0, 0, 0, 0, 0, 0, 0, 0};
  for (int d = j; d < D_; d += 8) {
    float xv = xr[d] + bo[d];
    const float* wg = Wg + d * E_;
#pragma unroll
    for (int e = 0; e < 8; e++) part[e] += xv * wg[e];
  }
#pragma unroll
  for (int off = 1; off < 8; off <<= 1)
#pragma unroll
    for (int e = 0; e < 8; e++) part[e] += __shfl_xor(part[e], off);
  if (j == 0) {
#pragma unroll
    for (int e = 0; e < 8; e++) logits[(size_t)t * 8 + e] = part[e];
  }
}

// transpose_v. vb in [0, 4096)
__device__ __forceinline__ void dev_transpose_v(
    const unsigned short* __restrict__ vbuf, unsigned short* __restrict__ vT,
    int vb, unsigned short* sm) {
  int xg = vb & 63, yg = (vb >> 6) & 1, bh = vb >> 7;
  int b = bh >> 3, h = bh & 7;
  int s0 = xg * 32, d0 = yg * 32;
  int tx = threadIdx.x & 31, ty = threadIdx.x >> 5;
  const unsigned short* in = vbuf + (size_t)b * S_ * D_ + h * DH_;
#pragma unroll
  for (int j = 0; j < 4; j++)
    sm[(ty + j * 8) * 33 + tx] = in[(size_t)(s0 + ty + j * 8) * D_ + d0 + tx];
  __syncthreads();
  unsigned short* out = vT + (size_t)bh * DH_ * S_;
#pragma unroll
  for (int j = 0; j < 4; j++)
    out[(size_t)(d0 + ty + j * 8) * S_ + s0 + tx] = sm[tx * 33 + ty + j * 8];
}

// ===========================================================================
// prep_a: memsets + split2h(x) + split2h(Wqkv) + cvt_f16 + cvt_bf16 +
//         transpose_w1 + transpose_w2 + wg2.   grid 16469 x 256.
// ===========================================================================
__global__ __launch_bounds__(256) void prep_a(
    const float* __restrict__ x, const float* __restrict__ Wqkv,
    const float* __restrict__ Wo, const float* __restrict__ W1,
    const float* __restrict__ W2, const float* __restrict__ Wg,
    unsigned short* __restrict__ xh, unsigned short* __restrict__ xls,
    unsigned short* __restrict__ Wqh, unsigned short* __restrict__ Wqls,
    f16* __restrict__ Wvh, bf16* __restrict__ Wob,
    bf16* __restrict__ W1t, bf16* __restrict__ W2t, float* __restrict__ Wg2,
    int* __restrict__ rowtok, float* __restrict__ dacc) {
  __shared__ float smem[32 * 33];
  int bid = blockIdx.x;
  if (bid < 68) { rowtok[bid * 256 + threadIdx.x] = -1; return; }
  bid -= 68;
  if (bid < 1) { if (threadIdx.x < 32) dacc[threadIdx.x] = 0.f; return; }
  bid -= 1;
  if (bid < 4096) { dev_split2h(x, xh, xls, TOK_ * D_, bid); return; }
  bid -= 4096;
  if (bid < 512) { dev_split2h(Wqkv, Wqh, Wqls, 1024 * D_, bid); return; }
  bid -= 512;
  if (bid < 256) { dev_cvt_f16(Wqkv + (size_t)1024 * D_, Wvh, D_ * D_, bid); return; }
  bid -= 256;
  if (bid < 256) { dev_cvt_bf16(Wo, Wob, D_ * D_, bid); return; }
  bid -= 256;
  if (bid < 5632) { dev_transpose_w1(W1, W1t, bid, smem); return; }
  bid -= 5632;
  if (bid < 5632) { dev_transpose_w2(W2, W2t, bid, smem); return; }
  bid -= 5632;
  dev_wg2(Wo, Wg, Wg2, bid);
}

// ===========================================================================
// wu2: Wu rows + fused split-2 write into Wqh/Wqls tail + bfull assembly.
// grid 256 x 256.
// ===========================================================================
__global__ __launch_bounds__(256) void wu_kernel2(const float* __restrict__ Wqkv,
    const float* __restrict__ Wg2, const float* __restrict__ bqkv,
    unsigned short* __restrict__ WqhT, unsigned short* __restrict__ WqlsT,
    float* __restrict__ bfull) {
  int gid = blockIdx.x * 256 + threadIdx.x;
  int row = gid >> 9, d = gid & 511;
  float acc = 0.f;
  if (row < 64) {
    int h = row >> 3, e = row & 7;
    const float* wv = Wqkv + (size_t)(1024 + h * 64) * 512 + d;
    const float* wg = Wg2 + h * 64 * 8 + e;
    for (int c = 0; c < 64; c++) acc += wv[(size_t)c * 512] * wg[c * 8];
  }
  f16 hv = (f16)acc;
  f16 lv = (f16)((acc - (float)hv) * 2048.f);
  WqhT[gid] = h2us(hv);
  WqlsT[gid] = h2us(lv);
  if (gid < 1024) bfull[gid] = bqkv[gid];
  if (gid < 128) {
    float bacc = 0.f;
    if (gid < 64) {
      int h = gid >> 3, e = gid & 7;
      for (int c = 0; c < 64; c++)
        bacc += bqkv[1024 + h * 64 + c] * Wg2[(h * 64 + c) * 8 + e];
    }
    bfull[1024 + gid] = bacc;
  }
}

// ===========================================================================
// dev_gemm_split2 (fp16 split-2 q,k,U GEMM) and dev_gemm_vf16 (v GEMM)
// fused into gemm_qv.  grid 832 x 256.  LDS 64 KB shared between branches.
// ===========================================================================
__device__ void dev_gemm_split2(
    const f16* __restrict__ Ah, const f16* __restrict__ Als,
    const f16* __restrict__ Bh, const f16* __restrict__ Bls,
    const float* __restrict__ bias, float* __restrict__ C, int N, int K,
    int lin, f16* sh) {
  f16* As0 = sh;
  f16* As1 = sh + 8192;
  f16* Bs0 = sh + 16384;
  f16* Bs1 = sh + 24576;
  int tid = threadIdx.x;
  int w = tid >> 6, lane = tid & 63;
  int lg = lane >> 4, li = lane & 15;
  int aa = lin / 72, t = lin % 72;
  size_t m0 = (size_t)((t & 7) + 8 * aa) * 128;
  int n0 = (t >> 3) * 128;
  int wm = w >> 1, wn = w & 1;
  f32x4 accA[4][4] = {};
  f32x4 accB[4][4] = {};

  int rowA[4], scA[4];
#pragma unroll
  for (int j = 0; j < 4; j++) {
    int o = w * 4096 + j * 1024 + lane * 16;
    rowA[j] = o >> 7;
    scA[j] = ((o >> 4) & 7) ^ (rowA[j] & 7);
  }

  for (int k0 = 0; k0 < K; k0 += 64) {
#pragma unroll
    for (int j = 0; j < 4; j++) {
      int o = w * 4096 + j * 1024 + lane * 16;
      size_t sa = (m0 + rowA[j]) * (size_t)K + k0 + scA[j] * 8;
      size_t sb = ((size_t)n0 + rowA[j]) * K + k0 + scA[j] * 8;
      gload16(Ah + sa, (char*)As0 + o);
      gload16(Als + sa, (char*)As1 + o);
      gload16(Bh + sb, (char*)Bs0 + o);
      gload16(Bls + sb, (char*)Bs1 + o);
    }
    __syncthreads();
#pragma unroll
    for (int ks = 0; ks < 2; ks++) {
      f16x8 afh[4], afl[4], bfh[4], bfl[4];
#pragma unroll
      for (int mi = 0; mi < 4; mi++) {
        int row = wm * 64 + mi * 16 + li;
        int cb = (lg * 16 + ks * 64) ^ ((row & 7) << 4);
        afh[mi] = *(const f16x8*)((char*)As0 + row * 128 + cb);
        afl[mi] = *(const f16x8*)((char*)As1 + row * 128 + cb);
      }
#pragma unroll
      for (int ni = 0; ni < 4; ni++) {
        int row = wn * 64 + ni * 16 + li;
        int cb = (lg * 16 + ks * 64) ^ ((row & 7) << 4);
        bfh[ni] = *(const f16x8*)((char*)Bs0 + row * 128 + cb);
        bfl[ni] = *(const f16x8*)((char*)Bs1 + row * 128 + cb);
      }
#pragma unroll
      for (int mi = 0; mi < 4; mi++)
#pragma unroll
        for (int ni = 0; ni < 4; ni++) {
          accA[mi][ni] = MFMAH(afh[mi], bfh[ni], accA[mi][ni]);
          accB[mi][ni] = MFMAH(afh[mi], bfl[ni], accB[mi][ni]);
          accB[mi][ni] = MFMAH(afl[mi], bfh[ni], accB[mi][ni]);
        }
    }
    __syncthreads();
  }
#pragma unroll
  for (int mi = 0; mi < 4; mi++)
#pragma unroll
    for (int ni = 0; ni < 4; ni++)
#pragma unroll
      for (int r = 0; r < 4; r++) {
        size_t m = m0 + wm * 64 + mi * 16 + lg * 4 + r;
        int c = n0 + wn * 64 + ni * 16 + li;
        C[m * (size_t)N + c] = accA[mi][ni][r] + accB[mi][ni][r] * C11 + bias[c];
      }
}

__device__ void dev_gemm_vf16(
    const f16* __restrict__ A, const f16* __restrict__ Bt,
    const float* __restrict__ bias, f16* __restrict__ Cout, int N, int K,
    int vb, f16* sh) {
  f16* Al = sh;
  f16* Bl = sh + 8192;
  int tid = threadIdx.x;
  int w = tid >> 6, lane = tid & 63;
  int lg = lane >> 4, li = lane & 15;
  size_t arow0 = (size_t)(vb >> 2) * 128;
  int n0 = (vb & 3) * 128;

  int rowA[4], scA[4];
#pragma unroll
  for (int j = 0; j < 4; j++) {
    int o = w * 4096 + j * 1024 + lane * 16;
    rowA[j] = o >> 7;
    scA[j] = ((o >> 4) & 7) ^ (rowA[j] & 7);
  }
  int wm = w >> 1, wn = w & 1;
  f32x4 acc[4][4] = {};

  for (int k0 = 0; k0 < K; k0 += 64) {
#pragma unroll
    for (int j = 0; j < 4; j++) {
      int o = w * 4096 + j * 1024 + lane * 16;
      gload16(A + (arow0 + rowA[j]) * (size_t)K + k0 + scA[j] * 8, (char*)Al + o);
      gload16(Bt + (size_t)(n0 + rowA[j]) * K + k0 + scA[j] * 8, (char*)Bl + o);
    }
    __syncthreads();
#pragma unroll
    for (int ks = 0; ks < 2; ks++) {
      f16x8 af[4], bfr[4];
#pragma unroll
      for (int mi = 0; mi < 4; mi++) {
        int row = wm * 64 + mi * 16 + li;
        int cb = (lg * 16 + ks * 64) ^ ((row & 7) << 4);
        af[mi] = *(const f16x8*)((char*)Al + row * 128 + cb);
      }
#pragma unroll
      for (int ni = 0; ni < 4; ni++) {
        int row = wn * 64 + ni * 16 + li;
        int cb = (lg * 16 + ks * 64) ^ ((row & 7) << 4);
        bfr[ni] = *(const f16x8*)((char*)Bl + row * 128 + cb);
      }
#pragma unroll
      for (int mi = 0; mi < 4; mi++)
#pragma unroll
        for (int ni = 0; ni < 4; ni++)
          acc[mi][ni] = MFMAH(af[mi], bfr[ni], acc[mi][ni]);
    }
    __syncthreads();
  }
#pragma unroll
  for (int mi = 0; mi < 4; mi++)
#pragma unroll
    for (int ni = 0; ni < 4; ni++)
#pragma unroll
      for (int r = 0; r < 4; r++) {
        size_t m = arow0 + wm * 64 + mi * 16 + lg * 4 + r;
        int c = n0 + wn * 64 + ni * 16 + li;
        Cout[m * (size_t)N + c] = (f16)(acc[mi][ni][r] + bias[c]);
      }
}

__global__ __launch_bounds__(256) void gemm_qv(
    const f16* __restrict__ Ah, const f16* __restrict__ Als,
    const f16* __restrict__ Bh, const f16* __restrict__ Bls,
    const float* __restrict__ bfull, float* __restrict__ qku32,
    const f16* __restrict__ Wvh, const float* __restrict__ bv,
    f16* __restrict__ vbuf) {
  __shared__ f16 sh[4 * 128 * 64];
  int bid = blockIdx.x;
  if (bid < 576)
    dev_gemm_split2(Ah, Als, Bh, Bls, bfull, qku32, NQKU_, D_, bid, sh);
  else
    dev_gemm_vf16(Ah, Wvh, bv, vbuf, D_, D_, bid - 576, sh);
}

// ===========================================================================
// prep_e: ksplit + transpose_u + xwg + transpose_v.  grid 8576 x 256.
// ===========================================================================
__global__ __launch_bounds__(256) void prep_e(
    const float* __restrict__ qku, unsigned short* __restrict__ kh,
    unsigned short* __restrict__ kls, f16* __restrict__ U2T,
    const float* __restrict__ x, const float* __restrict__ bo,
    const float* __restrict__ Wg, float* __restrict__ logits,
    const unsigned short* __restrict__ vbuf, unsigned short* __restrict__ vT) {
  __shared__ float smem[64 * 132];
  int bid = blockIdx.x;
  if (bid < 4096) { dev_ksplit(qku, kh, kls, bid); return; }
  bid -= 4096;
  if (bid < 128) { dev_transpose_u(qku, U2T, bid & 31, bid >> 5, smem); return; }
  bid -= 128;
  if (bid < 256) { dev_xwg(x, bo, Wg, logits, bid); return; }
  bid -= 256;
  dev_transpose_v(vbuf, vT, bid, (unsigned short*)smem);
}

// ---------------------------------------------------------------------------
// MFMA GEMM NT bf16 (FFN). 128x128 tile, BK=64, 256 thr.
// MODE 2: FFN1 (LeakyReLU, out bf16)  MODE 3: FFN2 (bias, out bf16)
// Meta (ebase/ecnt) recomputed per block from kept_be (no finalize kernel).
// ---------------------------------------------------------------------------
template <int MODE>
__global__ __launch_bounds__(256) void gemm_mfma(
    const bf16* __restrict__ A, const bf16* __restrict__ Bt,
    const float* __restrict__ bias, void* __restrict__ Cout, int N, int K,
    const int* __restrict__ kept_be) {
  __shared__ bf16 Al[128 * 64];
  __shared__ bf16 Bl[128 * 64];
  int tid = threadIdx.x;
  int w = tid >> 6, lane = tid & 63;
  int lg = lane >> 4, li = lane & 15;
  int e = blockIdx.z;
  int ecnt_e = 0, ebase_e = 0;
  {
    int base = 0;
    for (int ee = 0; ee < 8; ee++) {
      int tot = 0;
#pragma unroll
      for (int b = 0; b < 4; b++) tot += kept_be[b * 8 + ee];
      tot = min(tot, 4 * CAP_);
      if (ee == e) { ecnt_e = tot; ebase_e = base; }
      base += (tot + 127) & ~127;
    }
  }
  int r0 = blockIdx.y * 128;
  if (r0 >= ecnt_e) return;
  size_t arow0 = (size_t)(ebase_e + r0);
  int n0 = blockIdx.x * 128;
  const bf16* Bexp = Bt + (size_t)e * N * K;

  int rowA[4], scA[4];
#pragma unroll
  for (int j = 0; j < 4; j++) {
    int o = w * 4096 + j * 1024 + lane * 16;
    rowA[j] = o >> 7;
    scA[j] = ((o >> 4) & 7) ^ (rowA[j] & 7);
  }
  int wm = w >> 1, wn = w & 1;
  f32x4 acc[4][4] = {};

  for (int k0 = 0; k0 < K; k0 += 64) {
#pragma unroll
    for (int j = 0; j < 4; j++) {
      int o = w * 4096 + j * 1024 + lane * 16;
      gload16(A + (arow0 + rowA[j]) * (size_t)K + k0 + scA[j] * 8, (char*)Al + o);
      gload16(Bexp + (size_t)(n0 + rowA[j]) * K + k0 + scA[j] * 8, (char*)Bl + o);
    }
    __syncthreads();
#pragma unroll
    for (int ks = 0; ks < 2; ks++) {
      bf16x8 af[4], bfr[4];
#pragma unroll
      for (int mi = 0; mi < 4; mi++) {
        int row = wm * 64 + mi * 16 + li;
        int cb = (lg * 16 + ks * 64) ^ ((row & 7) << 4);
        af[mi] = *(const bf16x8*)((char*)Al + row * 128 + cb);
      }
#pragma unroll
      for (int ni = 0; ni < 4; ni++) {
        int row = wn * 64 + ni * 16 + li;
        int cb = (lg * 16 + ks * 64) ^ ((row & 7) << 4);
        bfr[ni] = *(const bf16x8*)((char*)Bl + row * 128 + cb);
      }
#pragma unroll
      for (int mi = 0; mi < 4; mi++)
#pragma unroll
        for (int ni = 0; ni < 4; ni++)
          acc[mi][ni] = MFMA16(af[mi], bfr[ni], acc[mi][ni]);
    }
    __syncthreads();
  }

#pragma unroll
  for (int mi = 0; mi < 4; mi++) {
#pragma unroll
    for (int ni = 0; ni < 4; ni++) {
#pragma unroll
      for (int r = 0; r < 4; r++) {
        size_t m = arow0 + wm * 64 + mi * 16 + lg * 4 + r;
        int c = n0 + wn * 64 + ni * 16 + li;
        float v = acc[mi][ni][r];
        if constexpr (MODE == 2) {
          if (c < HID_) {
            v += bias[e * HID_ + c];
            v = (v > 0.f) ? v : 0.01f * v;
            ((bf16*)Cout)[m * (size_t)HIDP_ + c] = __float2bfloat16(v);
          } else {
            ((bf16*)Cout)[m * (size_t)HIDP_ + c] = __float2bfloat16(0.f);
          }
        } else {
          v += bias[e * D_ + c];
          ((bf16*)Cout)[m * (size_t)N + c] = __float2bfloat16(v);
        }
      }
    }
  }
}

// ===========================================================================
// wo_rg: Wo-projection GEMM (bias+resid, out fp32) + reduce_gate fused.
// grid 288 x 256.
// ===========================================================================
__device__ void dev_gemm_wo(
    const bf16* __restrict__ A, const bf16* __restrict__ Bt,
    const float* __restrict__ bias, const float* __restrict__ resid,
    float* __restrict__ Cout, int vb, bf16* sh) {
  bf16* Al = sh;
  bf16* Bl = sh + 8192;
  const int N = D_, K = D_;
  int tid = threadIdx.x;
  int w = tid >> 6, lane = tid & 63;
  int lg = lane >> 4, li = lane & 15;
  size_t arow0 = (size_t)(vb >> 2) * 128;
  int n0 = (vb & 3) * 128;

  int rowA[4], scA[4];
#pragma unroll
  for (int j = 0; j < 4; j++) {
    int o = w * 4096 + j * 1024 + lane * 16;
    rowA[j] = o >> 7;
    scA[j] = ((o >> 4) & 7) ^ (rowA[j] & 7);
  }
  int wm = w >> 1, wn = w & 1;
  f32x4 acc[4][4] = {};

  for (int k0 = 0; k0 < K; k0 += 64) {
#pragma unroll
    for (int j = 0; j < 4; j++) {
      int o = w * 4096 + j * 1024 + lane * 16;
      gload16(A + (arow0 + rowA[j]) * (size_t)K + k0 + scA[j] * 8, (char*)Al + o);
      gload16(Bt + (size_t)(n0 + rowA[j]) * K + k0 + scA[j] * 8, (char*)Bl + o);
    }
    __syncthreads();
#pragma unroll
    for (int ks = 0; ks < 2; ks++) {
      bf16x8 af[4], bfr[4];
#pragma unroll
      for (int mi = 0; mi < 4; mi++) {
        int row = wm * 64 + mi * 16 + li;
        int cb = (lg * 16 + ks * 64) ^ ((row & 7) << 4);
        af[mi] = *(const bf16x8*)((char*)Al + row * 128 + cb);
      }
#pragma unroll
      for (int ni = 0; ni < 4; ni++) {
        int row = wn * 64 + ni * 16 + li;
        int cb = (lg * 16 + ks * 64) ^ ((row & 7) << 4);
        bfr[ni] = *(const bf16x8*)((char*)Bl + row * 128 + cb);
      }
#pragma unroll
      for (int mi = 0; mi < 4; mi++)
#pragma unroll
        for (int ni = 0; ni < 4; ni++)
          acc[mi][ni] = MFMA16(af[mi], bfr[ni], acc[mi][ni]);
    }
    __syncthreads();
  }
#pragma unroll
  for (int mi = 0; mi < 4; mi++)
#pragma unroll
    for (int ni = 0; ni < 4; ni++)
#pragma unroll
      for (int r = 0; r < 4; r++) {
        size_t m = arow0 + wm * 64 + mi * 16 + lg * 4 + r;
        int c = n0 + wn * 64 + ni * 16 + li;
        Cout[m * (size_t)N + c] = acc[mi][ni][r] + bias[c] + resid[m * (size_t)N + c];
      }
}

__device__ void dev_reduce_gate(
    const float* __restrict__ xwg, const float* __restrict__ part,
    int* __restrict__ e1a, int* __restrict__ e2a,
    float* __restrict__ g1a, float* __restrict__ g2a, int* __restrict__ use2a,
    float* __restrict__ dacc, int vb) {
  int t = vb * 256 + threadIdx.x;
  int b = t >> 11, s = t & 2047;
  float lg[8];
#pragma unroll
  for (int e = 0; e < 8; e++) lg[e] = xwg[(size_t)t * 8 + e];
  for (int h = 0; h < 8; h++) {
    const float* pp = part + ((size_t)(b * 8 + h) * S_ + s) * 8;
#pragma unroll
    for (int e = 0; e < 8; e++) lg[e] += pp[e];
  }
  float mx = lg[0];
#pragma unroll
  for (int e = 1; e < 8; e++) mx = fmaxf(mx, lg[e]);
  float p[8], se = 0.f;
#pragma unroll
  for (int e = 0; e < 8; e++) { p[e] = expf(lg[e] - mx); se += p[e]; }
  float inv = 1.f / se;
#pragma unroll
  for (int e = 0; e < 8; e++) p[e] *= inv;
  float lse = logf(se) + mx;
  int a1 = 0; float m1 = p[0];
#pragma unroll
  for (int e = 1; e < 8; e++) if (p[e] > m1) { m1 = p[e]; a1 = e; }
  int a2 = -1; float m2 = -1.f;
#pragma unroll
  for (int e = 0; e < 8; e++) if (e != a1 && p[e] > m2) { m2 = p[e]; a2 = e; }
  e1a[t] = a1; e2a[t] = a2; g1a[t] = m1; g2a[t] = m2;
  use2a[t] = (m2 > 0.2f) ? 1 : 0;
  float z = lse * lse;
  float pr[8];
#pragma unroll
  for (int e = 0; e < 8; e++) pr[e] = p[e];
#pragma unroll
  for (int off = 1; off < 64; off <<= 1) {
#pragma unroll
    for (int e = 0; e < 8; e++) pr[e] += __shfl_xor(pr[e], off);
    z += __shfl_xor(z, off);
  }
  float dcnt[8];
#pragma unroll
  for (int e = 0; e < 8; e++) dcnt[e] = (float)__popcll(__ballot(a1 == e));
  if ((threadIdx.x & 63) == 0) {
#pragma unroll
    for (int e = 0; e < 8; e++) {
      atomicAdd(&dacc[e], dcnt[e]);
      atomicAdd(&dacc[8 + e], pr[e]);
    }
    atomicAdd(&dacc[16], z);
  }
}

__global__ __launch_bounds__(256) void wo_rg(
    const bf16* __restrict__ attnb, const bf16* __restrict__ Wob,
    const float* __restrict__ bo, const float* __restrict__ x,
    float* __restrict__ o2,
    const float* __restrict__ xwg, const float* __restrict__ part,
    int* __restrict__ e1a, int* __restrict__ e2a,
    float* __restrict__ g1a, float* __restrict__ g2a, int* __restrict__ use2a,
    float* __restrict__ dacc) {
  __shared__ bf16 sh[2 * 128 * 64];
  int bid = blockIdx.x;
  if (bid < 256) dev_gemm_wo(attnb, Wob, bo, x, o2, bid, sh);
  else dev_reduce_gate(xwg, part, e1a, e2a, g1a, g2a, use2a, dacc, bid - 256);
}

// ---------------------------------------------------------------------------
// attn_fused (fp16 split-2): 4-wave blocks, 64 q-rows, KV tile 64.
// (round-16 body — measured best)
// ---------------------------------------------------------------------------
__global__ __launch_bounds__(256, 4) void attn_fused(
    const float* __restrict__ qku,
    const f16* __restrict__ kh, const f16* __restrict__ kls,
    const f16* __restrict__ vT, const f16* __restrict__ U2T,
    bf16* __restrict__ attnb, float* __restrict__ part) {
  __shared__ f16 Ks0[64 * 64];
  __shared__ f16 Ks1[64 * 64];
  __shared__ f16 Vtl[64 * 64];      // [d][key]
  __shared__ f16 Ut[16 * 64];       // rows 0..7 = U-hi[e], rows 8..15 = U-lo*2048
  __shared__ f16 Pl[4][16 * 40];    // per-wave P, 16 q x 32 keys, stride 80B
  int bid = blockIdx.x;
  int xcd = bid & 7, idx = bid >> 3; // idx 0..127
  int bh = (idx >> 5) * 8 + xcd;     // b = idx>>5, h = xcd
  int qt = idx & 31;
  int b = bh >> 3, h = bh & 7, q0 = qt * 64;
  int tid = threadIdx.x, w = tid >> 6, lane = tid & 63;
  int lg = lane >> 4, qi = lane & 15;
  const float KS = 0.125f * 1.44269504089f;   // exp2 domain
  const float KS2 = KS * C11;

  // q split-2 in-register (hi + lo*2048)
  const float* qsrc = qku + (size_t)(b * S_ + q0 + w * 16 + qi) * NQKU_ + h * 64 + lg * 8;
  f16x8 qh[2], qls[2];
#pragma unroll
  for (int ks = 0; ks < 2; ks++) {
#pragma unroll
    for (int i = 0; i < 8; i++) {
      float xv = qsrc[ks * 32 + i];
      f16 hh = (f16)xv;
      f16 ll = (f16)((xv - (float)hh) * 2048.f);
      qh[ks][i] = hh;
      qls[ks][i] = ll;
    }
  }

  f32x4 oacc[4] = {};
  f32x4 raccA = {0.f, 0.f, 0.f, 0.f};
  f32x4 raccB = {0.f, 0.f, 0.f, 0.f};
  float mrun = -1e30f, lrun = 0.f;
  const f16* Vbase = vT + (size_t)bh * DH_ * S_;
  char* pw = (char*)&Pl[w][0];

  for (int kt = 0; kt < S_ / 64; kt++) {
    // stage K splits (8KB each) + V tile (8KB) across 4 waves; U (2KB) w<2
#pragma unroll
    for (int j = 0; j < 2; j++) {
      int o = w * 2048 + j * 1024 + lane * 16;
      int row = o >> 7;                       // 0..63
      int sc = ((o >> 4) & 7) ^ (row & 7);
      size_t srcK = ((size_t)bh * S_ + kt * 64 + row) * 64 + sc * 8;
      gload16(kh + srcK, (char*)Ks0 + o);
      gload16(kls + srcK, (char*)Ks1 + o);
      gload16(Vbase + (size_t)row * S_ + kt * 64 + sc * 8, (char*)Vtl + o);
    }
    if (w < 2) {
      int o = w * 1024 + lane * 16;
      int rowu = o >> 7;                      // 0..15
      int scu = ((o >> 4) & 7) ^ (rowu & 7);
      gload16(U2T + ((size_t)(bh * 16 + rowu) * 2048 + kt * 64 + scu * 8),
              (char*)Ut + o);
    }
    __syncthreads();

    // precise scores: 3-product fp16 split-2; lo accumulator is nb-local.
    f32x4 sA[4];
    float tmax = -1e30f;
#pragma unroll
    for (int nb = 0; nb < 4; nb++) {
      f32x4 a = {0.f, 0.f, 0.f, 0.f};
      f32x4 bq = {0.f, 0.f, 0.f, 0.f};
      int row = nb * 16 + qi;
#pragma unroll
      for (int ks = 0; ks < 2; ks++) {
        int cb = (lg * 16 + ks * 64) ^ ((row & 7) << 4);
        f16x8 k0 = *(const f16x8*)((char*)Ks0 + row * 128 + cb);
        f16x8 k1 = *(const f16x8*)((char*)Ks1 + row * 128 + cb);
        a = MFMAH(k0, qh[ks], a);
        bq = MFMAH(k0, qls[ks], bq);
        bq = MFMAH(k1, qh[ks], bq);
      }
#pragma unroll
      for (int r = 0; r < 4; r++) {
        float v = a[r] * KS + bq[r] * KS2;
        sA[nb][r] = v;
        tmax = fmaxf(tmax, v);
      }
    }
    // online softmax with defer-max (THR=8 log2)
    tmax = fmaxf(tmax, __shfl_xor(tmax, 16));
    tmax = fmaxf(tmax, __shfl_xor(tmax, 32));
    float fsc = 1.f;
    if (!__all(tmax <= mrun + 8.f)) {
      float mnew = fmaxf(mrun, tmax);
      fsc = exp2f(mrun - mnew);
      mrun = mnew;
#pragma unroll
      for (int r = 0; r < 4; r++) { raccA[r] *= fsc; raccB[r] *= fsc; }
#pragma unroll
      for (int db = 0; db < 4; db++)
#pragma unroll
        for (int r = 0; r < 4; r++) oacc[db][r] *= fsc;
    }
    float psum = 0.f;
#pragma unroll
    for (int nb = 0; nb < 4; nb++)
#pragma unroll
      for (int r = 0; r < 4; r++) {
        float pv = exp2f(sA[nb][r] - mrun);
        sA[nb][r] = pv;
        psum += pv;
      }
    psum += __shfl_xor(psum, 16);
    psum += __shfl_xor(psum, 32);
    lrun = lrun * fsc + psum;

    // per 32-key chunk (c=0,1): write P hi -> PV + P.U; write P lo -> P.U
#pragma unroll
    for (int c = 0; c < 2; c++) {
#pragma unroll
      for (int nbL = 0; nbL < 2; nbL++)
#pragma unroll
        for (int rp = 0; rp < 2; rp++) {
          int nb = c * 2 + nbL;
          float p0 = sA[nb][rp * 2], p1 = sA[nb][rp * 2 + 1];
          h16x2 hp = __builtin_amdgcn_cvt_pkrtz(p0, p1);
          int keyl = 4 * lg + 2 * rp + 16 * nbL;
          *(unsigned*)(pw + qi * 80 + keyl * 2) = *(unsigned*)&hp;
        }
      f16x8 pf = *(const f16x8*)(pw + qi * 80 + lg * 16);
#pragma unroll
      for (int db = 0; db < 4; db++) {
        int row = db * 16 + qi;
        int cb = (lg * 16 + c * 64) ^ ((row & 7) << 4);
        f16x8 vf = *(const f16x8*)((char*)Vtl + row * 128 + cb);
        oacc[db] = MFMAH(vf, pf, oacc[db]);
      }
      int ua = qi * 128 + ((c * 64 + lg * 16) ^ ((qi & 7) << 4));
      f16x8 uf = *(const f16x8*)((char*)Ut + ua);
      raccA = MFMAH(uf, pf, raccA);
      // P lo into the same slot (wave LDS ops in order: pf read drains first)
#pragma unroll
      for (int nbL = 0; nbL < 2; nbL++)
#pragma unroll
        for (int rp = 0; rp < 2; rp++) {
          int nb = c * 2 + nbL;
          float p0 = sA[nb][rp * 2], p1 = sA[nb][rp * 2 + 1];
          h16x2 hp = __builtin_amdgcn_cvt_pkrtz(p0, p1);
          float b0 = (float)hp[0], b1 = (float)hp[1];
          h16x2 lp = __builtin_amdgcn_cvt_pkrtz((p0 - b0) * 2048.f, (p1 - b1) * 2048.f);
          int keyl = 4 * lg + 2 * rp + 16 * nbL;
          *(unsigned*)(pw + qi * 80 + keyl * 2) = *(unsigned*)&lp;
        }
      f16x8 pfl = *(const f16x8*)(pw + qi * 80 + lg * 16);
      raccB = MFMAH(uf, pfl, raccB);
    }
    __syncthreads();
  }

  float inv = 1.f / lrun;
  // routing epilogue:
  // raccA(lg<2)=Uh.Ph, raccA(lg>=2)=Uls.Ph, raccB(lg<2)=Uh.Pls, raccB(lg>=2)=Uls.Pls
  f32x4 pA, pB;
#pragma unroll
  for (int r = 0; r < 4; r++) {
    pA[r] = __shfl_xor(raccA[r], 32);
    pB[r] = __shfl_xor(raccB[r], 32);
  }
  if (lg < 2) {
    float* dst = part + ((size_t)bh * S_ + q0 + w * 16 + qi) * 8 + lg * 4;
#pragma unroll
    for (int r = 0; r < 4; r++)
      dst[r] = (raccA[r] + C11 * (pA[r] + raccB[r]) + C22 * pB[r]) * inv;
  }
  // value epilogue: O^T -> O via wave-private 2KB scratch in Ks0
  char* ow = (char*)Ks0 + w * 2048;
#pragma unroll
  for (int db = 0; db < 4; db++)
#pragma unroll
    for (int rp = 0; rp < 2; rp++) {
      int d = db * 16 + lg * 4 + rp * 2;
      unsigned pk = bf16pk(oacc[db][rp * 2] * inv, oacc[db][rp * 2 + 1] * inv);
      int addr = (qi * 128 + d * 2) ^ ((qi & 7) << 4);
      *(unsigned*)(ow + addr) = pk;
    }
#pragma unroll
  for (int j = 0; j < 2; j++) {
    int o = j * 1024 + lane * 16;
    int q = o >> 7;
    int c16 = (o >> 4) & 7;
    int sc = c16 ^ (q & 7);
    bf16x8 vv = *(const bf16x8*)(ow + q * 128 + sc * 16);
    *(bf16x8*)(attnb + ((size_t)(b * S_ + q0 + w * 16 + q)) * D_ + h * DH_ + c16 * 8) = vv;
  }
}

// ---------------------------------------------------------------------------
// Capacity scan: exact cumsum order, parallelized (8 waves, 2-pass).
// ---------------------------------------------------------------------------
__global__ __launch_bounds__(512) void scan_kernel(
    const int* __restrict__ e1a, const int* __restrict__ e2a,
    const int* __restrict__ use2a,
    int* __restrict__ posArr, int* __restrict__ kept_be) {
  __shared__ int wcnt[8][8];
  int b = blockIdx.x;
  int w = threadIdx.x >> 6, lane = threadIdx.x & 63;
  unsigned long long below = (1ull << lane) - 1ull;
  int cnt[8] = {0, 0, 0, 0, 0, 0, 0, 0};
  int ev[8], av[8];
#pragma unroll
  for (int it = 0; it < 8; it++) {
    int i = w * 512 + it * 64 + lane;
    int s = i & (S_ - 1);
    int t = b * S_ + s;
    int e, a;
    if (i < S_) { e = e1a[t]; a = 1; }
    else        { e = e2a[t]; a = use2a[t]; }
    ev[it] = e; av[it] = a;
#pragma unroll
    for (int ee = 0; ee < 8; ee++)
      cnt[ee] += __popcll(__ballot(a && (e == ee)));
  }
  if (lane == 0)
#pragma unroll
    for (int ee = 0; ee < 8; ee++) wcnt[w][ee] = cnt[ee];
  __syncthreads();
  int run[8];
#pragma unroll
  for (int ee = 0; ee < 8; ee++) {
    int sB = 0;
    for (int ww = 0; ww < w; ww++) sB += wcnt[ww][ee];
    run[ee] = sB;
  }
#pragma unroll
  for (int it = 0; it < 8; it++) {
    int i = w * 512 + it * 64 + lane;
    int e = ev[it], a = av[it];
    int pos = -1;
#pragma unroll
    for (int ee = 0; ee < 8; ee++) {
      unsigned long long mask = __ballot(a && (e == ee));
      if (a && e == ee) pos = run[ee] + __popcll(mask & below);
      run[ee] += __popcll(mask);
    }
    posArr[b * (2 * S_) + i] = (a && pos < CAP_) ? pos : -1;
  }
  if (w == 7 && lane == 0)
#pragma unroll
    for (int ee = 0; ee < 8; ee++) kept_be[b * 8 + ee] = min(run[ee], CAP_);
}

// ---------------------------------------------------------------------------
// Scatter: compacted row lists + per-token combine info. Meta recomputed
// per block from kept_be; block 0 also writes aux-loss scalars (dacc ready).
// ---------------------------------------------------------------------------
__global__ __launch_bounds__(256) void scatter_kernel(
    const int* __restrict__ posArr, const int* __restrict__ e1a, const int* __restrict__ e2a,
    const float* __restrict__ g1a, const float* __restrict__ g2a,
    const int* __restrict__ kept_be, const float* __restrict__ dacc,
    int* __restrict__ rowtok, int* __restrict__ rowexp,
    int* __restrict__ tokidx, float* __restrict__ tokw, float* __restrict__ outs) {
  __shared__ int s_eb[8], s_bb[32];
  if (threadIdx.x == 0) {
    int base = 0;
    for (int e = 0; e < 8; e++) {
      int tot = 0;
      for (int b = 0; b < 4; b++) { s_bb[b * 8 + e] = tot; tot += kept_be[b * 8 + e]; }
      s_eb[e] = base;
      base += (tot + 127) & ~127;
    }
    if (blockIdx.x == 0) {
      float bal = 0.f;
      for (int e = 0; e < 8; e++)
        bal += (dacc[e] / (float)TOK_) * (dacc[8 + e] / (float)TOK_);
      bal *= (float)E_;
      float z = dacc[16] / (float)TOK_;
      outs[0] = 0.01f * bal + 0.001f * z;
      outs[1] = bal;
      outs[2] = z;
    }
  }
  __syncthreads();
  int gi = blockIdx.x * 256 + threadIdx.x;
  int b = gi >> 12, i = gi & 4095;
  int k = i >> 11, s = i & (S_ - 1);
  int t = b * S_ + s;
  int pos = posArr[gi];
  int idx = -1; float w = 0.f;
  if (pos >= 0) {
    int e = k ? e2a[t] : e1a[t];
    idx = s_eb[e] + s_bb[b * 8 + e] + pos;
    rowtok[idx] = t;
    rowexp[idx] = e;
    w = k ? g2a[t] : g1a[t];
  }
  tokidx[k * TOK_ + t] = idx;
  tokw[k * TOK_ + t] = w;
}

// ---------------------------------------------------------------------------
// LayerNorm per compacted row -> bf16.
// ---------------------------------------------------------------------------
__global__ __launch_bounds__(256) void ln_kernel(
    const float* __restrict__ o2, const int* __restrict__ rowtok,
    const int* __restrict__ rowexp, const float* __restrict__ ln_g,
    const float* __restrict__ ln_b, bf16* __restrict__ xn) {
  int row = blockIdx.x * 4 + (threadIdx.x >> 6);
  int lane = threadIdx.x & 63;
  int tok = rowtok[row];
  if (tok < 0) return;
  int e = rowexp[row];
  const float* xr = o2 + (size_t)tok * D_;
  float v[8], sum = 0.f, sq = 0.f;
#pragma unroll
  for (int j = 0; j < 8; j++) { v[j] = xr[lane * 8 + j]; sum += v[j]; sq += v[j] * v[j]; }
#pragma unroll
  for (int off = 1; off < 64; off <<= 1) { sum += __shfl_xor(sum, off); sq += __shfl_xor(sq, off); }
  float mu = sum / (float)D_;
  float var = sq / (float)D_ - mu * mu;
  float inv = rsqrtf(var + 1e-5f);
  bf16* xo = xn + (size_t)row * D_;
#pragma unroll
  for (int j = 0; j < 8; j++) {
    int d = lane * 8 + j;
    xo[d] = __float2bfloat16((v[j] - mu) * inv * ln_g[e * D_ + d] + ln_b[e * D_ + d]);
  }
}

// ---------------------------------------------------------------------------
// Combine: out = o2 + w1*y[idx1] + w2*y[idx2]   (y bf16)
// ---------------------------------------------------------------------------
__global__ __launch_bounds__(256) void combine_kernel(
    const float* __restrict__ o2, const bf16* __restrict__ y,
    const int* __restrict__ tokidx, const float* __restrict__ tokw,
    float* __restrict__ out) {
  size_t gi = (size_t)blockIdx.x * 256 + threadIdx.x;
  int t = (int)(gi >> 9);
  int d = (int)(gi & (D_ - 1));
  float v = o2[gi];
  int i1 = tokidx[t], i2 = tokidx[TOK_ + t];
  if (i1 >= 0) v += tokw[t] * __bfloat162float(y[(size_t)i1 * D_ + d]);
  if (i2 >= 0) v += tokw[TOK_ + t] * __bfloat162float(y[(size_t)i2 * D_ + d]);
  out[gi] = v;
}

// ---------------------------------------------------------------------------
extern "C" void kernel_launch(void* const* d_in, const int* in_sizes, int n_in,
                              void* d_out, int out_size, void* d_ws, size_t ws_size,
                              hipStream_t stream) {
  const float* x    = (const float*)d_in[0];
  const float* Wqkv = (const float*)d_in[1];
  const float* bqkv = (const float*)d_in[2];
  const float* Wo   = (const float*)d_in[3];
  const float* bo   = (const float*)d_in[4];
  const float* Wg   = (const float*)d_in[5];
  const float* ln_g = (const float*)d_in[6];
  const float* ln_b = (const float*)d_in[7];
  const float* W1   = (const float*)d_in[8];
  const float* b1   = (const float*)d_in[9];
  const float* W2   = (const float*)d_in[10];
  const float* b2   = (const float*)d_in[11];
  float* out = (float*)d_out;

  char* ws = (char*)d_ws;
  size_t off = 0;
  auto alloc = [&](size_t bytes) -> void* {
    void* p = ws + off;
    off = (off + bytes + 255) & ~(size_t)255;
    return p;
  };
  float* qku32 = (float*)alloc((size_t)TOK_ * NQKU_ * 4); // 37.7 MB
  f16*  vbuf   = (f16*)alloc((size_t)TOK_ * D_ * 2);
  f16*  vT     = (f16*)alloc((size_t)B_ * H_ * DH_ * S_ * 2);
  bf16* attnb  = (bf16*)alloc((size_t)TOK_ * D_ * 2);
  float* o2    = (float*)alloc((size_t)TOK_ * D_ * 4);
  f16*  xh     = (f16*)alloc((size_t)TOK_ * D_ * 2);
  f16*  xls    = (f16*)alloc((size_t)TOK_ * D_ * 2);
  f16*  Wqh    = (f16*)alloc((size_t)NQKU_ * D_ * 2);
  f16*  Wqls   = (f16*)alloc((size_t)NQKU_ * D_ * 2);
  f16*  Wvh    = (f16*)alloc((size_t)D_ * D_ * 2);
  bf16* Wob    = (bf16*)alloc((size_t)D_ * D_ * 2);
  bf16* W1t    = (bf16*)alloc((size_t)E_ * HIDP_ * D_ * 2);
  bf16* W2t    = (bf16*)alloc((size_t)E_ * D_ * HIDP_ * 2);
  bf16* xn     = (bf16*)alloc((size_t)RMAX_ * D_ * 2);
  bf16* hbuf   = (bf16*)alloc((size_t)RMAX_ * HIDP_ * 2);
  bf16* ybuf   = (bf16*)alloc((size_t)RMAX_ * D_ * 2);
  float* Wg2   = (float*)alloc(D_ * E_ * 4);
  float* bfull = (float*)alloc(NQKU_ * 4);
  f16*  U2T    = (f16*)alloc((size_t)32 * 16 * 2048 * 2);
  float* logits= (float*)alloc((size_t)TOK_ * 8 * 4);
  float* part  = (float*)alloc((size_t)B_ * H_ * S_ * 8 * 4);
  int*   e1a   = (int*)alloc(TOK_ * 4);
  int*   e2a   = (int*)alloc(TOK_ * 4);
  int*   use2a = (int*)alloc(TOK_ * 4);
  float* g1a   = (float*)alloc(TOK_ * 4);
  float* g2a   = (float*)alloc(TOK_ * 4);
  int*   posArr  = (int*)alloc(NASS_ * 4);
  int*   kept_be = (int*)alloc(32 * 4);
  int*   rowtok  = (int*)alloc(RMAX_ * 4);
  int*   rowexp  = (int*)alloc(RMAX_ * 4);
  int*   tokidx  = (int*)alloc(NASS_ * 4);
  float* tokw    = (float*)alloc(NASS_ * 4);
  float* dacc    = (float*)alloc(32 * 4);
  // kh/kls alias xh/xls (same size; prep_e runs after all consumers of xh/xls)
  f16* kh  = xh;
  f16* kls = xls;

  // 1. prep_a: memsets + all independent weight/input conversions
  prep_a<<<16469, 256, 0, stream>>>(x, Wqkv, Wo, W1, W2, Wg,
                                    (unsigned short*)xh, (unsigned short*)xls,
                                    (unsigned short*)Wqh, (unsigned short*)Wqls,
                                    Wvh, Wob, W1t, W2t, Wg2, rowtok, dacc);
  // 2. wu2: folded-gate weight rows + split-2 direct into Wqh/Wqls tail
  wu_kernel2<<<256, 256, 0, stream>>>(Wqkv, Wg2, bqkv,
      (unsigned short*)(Wqh + (size_t)1024 * D_),
      (unsigned short*)(Wqls + (size_t)1024 * D_), bfull);
  // 3. q,k,U split-2 GEMM + v GEMM in one launch
  gemm_qv<<<832, 256, 0, stream>>>(xh, xls, Wqh, Wqls, bfull, qku32,
                                   Wvh, bqkv + 1024, vbuf);
  // 4. routing/attention preps (kh/kls overwrite xh/xls — consumers done)
  prep_e<<<8576, 256, 0, stream>>>(qku32, (unsigned short*)kh,
                                   (unsigned short*)kls, U2T, x, bo, Wg,
                                   logits, (const unsigned short*)vbuf,
                                   (unsigned short*)vT);
  // 5. fused attention: value O + routing part in one pass
  attn_fused<<<dim3(1024), 256, 0, stream>>>(qku32, kh, kls, vT, U2T,
                                             attnb, part);
  // 6. Wo-projection GEMM + routing reduce in one launch
  wo_rg<<<288, 256, 0, stream>>>(attnb, Wob, bo, x, o2, logits, part,
                                 e1a, e2a, g1a, g2a, use2a, dacc);
  // 7. capacity scan
  scan_kernel<<<B_, 512, 0, stream>>>(e1a, e2a, use2a, posArr, kept_be);
  // 8. scatter (meta recomputed in-kernel; aux scalars from block 0)
  scatter_kernel<<<NASS_ / 256, 256, 0, stream>>>(posArr, e1a, e2a, g1a, g2a,
                                                  kept_be, dacc, rowtok, rowexp,
                                                  tokidx, tokw,
                                                  out + (size_t)TOK_ * D_);
  // 9. LayerNorm
  ln_kernel<<<RMAX_ / 4, 256, 0, stream>>>(o2, rowtok, rowexp, ln_g, ln_b, xn);
  // 10-11. expert FFN (meta recomputed per block from kept_be)
  gemm_mfma<2><<<dim3(HIDP_ / 128, 32, E_), 256, 0, stream>>>(xn, W1t, b1, hbuf,
                                                              HIDP_, D_, kept_be);
  gemm_mfma<3><<<dim3(D_ / 128, 32, E_), 256, 0, stream>>>(hbuf, W2t, b2, ybuf,
                                                           D_, HIDP_, kept_be);
  // 12. combine
  combine_kernel<<<(TOK_ * D_) / 256, 256, 0, stream>>>(o2, ybuf, tokidx, tokw, out);
}